// Round 1
// baseline (410.591 us; speedup 1.0000x reference)
//
#include <hip/hip_runtime.h>

#define XD 512
#define HEADS 8
#define DH 64
#define NSEQ 2048
#define NBATCH 4
#define NROWS (NBATCH*NSEQ)   // 8192

typedef __attribute__((ext_vector_type(8))) short bf16x8;
typedef __attribute__((ext_vector_type(8))) unsigned short u16x8;
typedef __attribute__((ext_vector_type(4))) float f32x4;

__device__ __forceinline__ unsigned short f2bf(float f) {
  union { float f; unsigned u; } v; v.f = f;
  return (unsigned short)((v.u + 0x7fffu + ((v.u >> 16) & 1u)) >> 16);
}

// ---------------- z path: LN(z) @ Wz -> silu -> z1,z2  (tiny) ----------------
__global__ __launch_bounds__(256) void zpath_kernel(
    const float* __restrict__ z, const float* __restrict__ g, const float* __restrict__ b,
    const float* __restrict__ Wz, float* __restrict__ z12) {
  int bb = blockIdx.x;            // batch
  int t = threadIdx.x;
  float zv[16];
  float mean = 0.f;
#pragma unroll
  for (int i = 0; i < 16; ++i) { zv[i] = z[bb * 16 + i]; mean += zv[i]; }
  mean *= (1.f / 16.f);
  float var = 0.f;
#pragma unroll
  for (int i = 0; i < 16; ++i) { float d = zv[i] - mean; var += d * d; }
  var *= (1.f / 16.f);
  float rs = rsqrtf(var + 1e-5f);
  float zn[16];
#pragma unroll
  for (int i = 0; i < 16; ++i) zn[i] = (zv[i] - mean) * rs * g[i] + b[i];
  for (int c = t; c < 1024; c += 256) {
    float acc = 0.f;
#pragma unroll
    for (int i = 0; i < 16; ++i) acc += zn[i] * Wz[i * 1024 + c];
    float s = acc / (1.f + __expf(-acc));   // silu
    z12[bb * 1024 + c] = s;
  }
}

// ---------------- x_mod = LN(x)*z1 + z2 -> bf16 [8192,512] ----------------
__global__ __launch_bounds__(256) void xmod_kernel(
    const float* __restrict__ x, const float* __restrict__ g, const float* __restrict__ b,
    const float* __restrict__ z12, unsigned short* __restrict__ xm) {
  int wave = threadIdx.x >> 6, lane = threadIdx.x & 63;
  int row = blockIdx.x * 4 + wave;
  const float* xr = x + (size_t)row * XD;
  float4 v0 = ((const float4*)xr)[lane * 2];
  float4 v1 = ((const float4*)xr)[lane * 2 + 1];
  float vv[8] = {v0.x, v0.y, v0.z, v0.w, v1.x, v1.y, v1.z, v1.w};
  float sum = 0.f, sq = 0.f;
#pragma unroll
  for (int i = 0; i < 8; ++i) { sum += vv[i]; sq += vv[i] * vv[i]; }
#pragma unroll
  for (int o = 32; o; o >>= 1) { sum += __shfl_xor(sum, o); sq += __shfl_xor(sq, o); }
  float mean = sum * (1.f / 512.f);
  float var = sq * (1.f / 512.f) - mean * mean;
  float rs = rsqrtf(var + 1e-5f);
  int bb = row >> 11;
  const float* zz = z12 + bb * 1024;
  int c0 = lane * 8;
  u16x8 o8;
#pragma unroll
  for (int i = 0; i < 8; ++i) {
    int c = c0 + i;
    float t = (vv[i] - mean) * rs * g[c] + b[c];
    t = t * zz[c] + zz[512 + c];
    o8[i] = f2bf(t);
  }
  *(u16x8*)(xm + (size_t)row * XD + c0) = o8;
}

// ---------------- weight transpose fp32[K,N] -> bf16 Wt[n*512+k] ----------------
__global__ __launch_bounds__(256) void wtrans_kernel(
    const float* __restrict__ W, unsigned short* __restrict__ Wt) {
  int idx = blockIdx.x * 256 + threadIdx.x;   // 0..262143 ; idx = n*512 + k
  int n = idx >> 9, k = idx & 511;
  Wt[idx] = f2bf(W[k * 512 + n]);
}

// ---------------- GEMM: C[8192,512] = A_bf16 @ W (Wt is [n][k] bf16) ----------------
// MODE 0: bf16 row-major out; MODE 1: per-head-transposed V out; MODE 2: fp32 out + bias
template <int MODE>
__global__ __launch_bounds__(256) void gemm_kernel(
    const unsigned short* __restrict__ A, const unsigned short* __restrict__ Wt,
    void* __restrict__ out, const float* __restrict__ bias) {
  int wid = blockIdx.x * 4 + (threadIdx.x >> 6);
  int lane = threadIdx.x & 63;
  int nt = wid & 7, mt = wid >> 3;              // nt: 0..7 (64-col tile), mt: 0..511
  int lr = lane & 15, lg = lane >> 4;
  const size_t a_base = (size_t)(mt * 16 + lr) * 512 + lg * 8;
  f32x4 acc[4] = {};
  for (int kc = 0; kc < 512; kc += 32) {
    bf16x8 a = *(const bf16x8*)(A + a_base + kc);
#pragma unroll
    for (int ns = 0; ns < 4; ++ns) {
      int col = nt * 64 + ns * 16 + lr;
      bf16x8 bf = *(const bf16x8*)(Wt + (size_t)col * 512 + kc + lg * 8);
      acc[ns] = __builtin_amdgcn_mfma_f32_16x16x32_bf16(a, bf, acc[ns], 0, 0, 0);
    }
  }
#pragma unroll
  for (int ns = 0; ns < 4; ++ns) {
    int col = nt * 64 + ns * 16 + lr;
#pragma unroll
    for (int j = 0; j < 4; ++j) {
      int row = mt * 16 + lg * 4 + j;
      float v = acc[ns][j];
      if (MODE == 0) {
        ((unsigned short*)out)[(size_t)row * 512 + col] = f2bf(v);
      } else if (MODE == 1) {
        int bb = row >> 11, n = row & 2047, h = col >> 6, d = col & 63;
        ((unsigned short*)out)[(((size_t)(bb * HEADS + h) * DH + d) << 11) + n] = f2bf(v);
      } else {
        ((float*)out)[(size_t)row * 512 + col] = v + bias[col];
      }
    }
  }
}

// ---------------- flash attention: wave per 16 q-rows per (b,h) ----------------
__global__ __launch_bounds__(256) void attn_kernel(
    const unsigned short* __restrict__ Q, const unsigned short* __restrict__ K,
    const unsigned short* __restrict__ VT, unsigned short* __restrict__ O) {
  __shared__ unsigned short p_lds[4][16 * 32];
  int widx = threadIdx.x >> 6, lane = threadIdx.x & 63;
  int wid = blockIdx.x * 4 + widx;
  int bh = wid >> 7;            // 0..31
  int qt = wid & 127;           // 0..127
  int b = bh >> 3, h = bh & 7;
  int lr = lane & 15, lg = lane >> 4;
  const size_t qk_row0 = ((size_t)b * NSEQ) * 512 + h * 64;
  size_t qaddr = qk_row0 + (size_t)(qt * 16 + lr) * 512 + lg * 8;
  bf16x8 q0 = *(const bf16x8*)(Q + qaddr);
  bf16x8 q1 = *(const bf16x8*)(Q + qaddr + 32);
  float m[4] = {-1e30f, -1e30f, -1e30f, -1e30f};
  float l[4] = {0.f, 0.f, 0.f, 0.f};
  f32x4 o[4] = {};
  const size_t vt_base = ((size_t)bh * DH) * (size_t)NSEQ;
  unsigned short* pw = p_lds[widx];

  for (int kc = 0; kc < NSEQ; kc += 32) {
    f32x4 s[2] = {};
#pragma unroll
    for (int kt = 0; kt < 2; ++kt) {
      size_t kaddr = qk_row0 + (size_t)(kc + kt * 16 + lr) * 512 + lg * 8;
      bf16x8 k0 = *(const bf16x8*)(K + kaddr);
      bf16x8 k1 = *(const bf16x8*)(K + kaddr + 32);
      s[kt] = __builtin_amdgcn_mfma_f32_16x16x32_bf16(q0, k0, s[kt], 0, 0, 0);
      s[kt] = __builtin_amdgcn_mfma_f32_16x16x32_bf16(q1, k1, s[kt], 0, 0, 0);
    }
    float alpha[4];
#pragma unroll
    for (int j = 0; j < 4; ++j) {
      float s0 = s[0][j] * 0.125f, s1 = s[1][j] * 0.125f;
      float cm = fmaxf(s0, s1);
#pragma unroll
      for (int o2 = 1; o2 < 16; o2 <<= 1) cm = fmaxf(cm, __shfl_xor(cm, o2));
      float mn = fmaxf(m[j], cm);
      alpha[j] = __expf(m[j] - mn);
      m[j] = mn;
      float p0 = __expf(s0 - mn);
      float p1 = __expf(s1 - mn);
      s[0][j] = p0; s[1][j] = p1;
      float rsum = p0 + p1;
#pragma unroll
      for (int o2 = 1; o2 < 16; o2 <<= 1) rsum += __shfl_xor(rsum, o2);
      l[j] = l[j] * alpha[j] + rsum;
    }
#pragma unroll
    for (int dt = 0; dt < 4; ++dt)
#pragma unroll
      for (int j = 0; j < 4; ++j) o[dt][j] *= alpha[j];
    // P (C-layout) -> LDS -> A-layout fragment
#pragma unroll
    for (int j = 0; j < 4; ++j) {
      int row = lg * 4 + j;
      pw[row * 32 + lr] = f2bf(s[0][j]);
      pw[row * 32 + 16 + lr] = f2bf(s[1][j]);
    }
    __syncthreads();
    bf16x8 pf = *(const bf16x8*)(pw + lr * 32 + lg * 8);
#pragma unroll
    for (int dt = 0; dt < 4; ++dt) {
      size_t vaddr = vt_base + (size_t)(dt * 16 + lr) * NSEQ + kc + lg * 8;
      bf16x8 vf = *(const bf16x8*)(VT + vaddr);
      o[dt] = __builtin_amdgcn_mfma_f32_16x16x32_bf16(pf, vf, o[dt], 0, 0, 0);
    }
    __syncthreads();
  }
  float inv[4];
#pragma unroll
  for (int j = 0; j < 4; ++j) inv[j] = 1.f / l[j];
#pragma unroll
  for (int dt = 0; dt < 4; ++dt) {
#pragma unroll
    for (int j = 0; j < 4; ++j) {
      int row = b * NSEQ + qt * 16 + lg * 4 + j;
      int col = h * 64 + dt * 16 + lr;
      O[(size_t)row * 512 + col] = f2bf(o[dt][j] * inv[j]);
    }
  }
}

extern "C" void kernel_launch(void* const* d_in, const int* in_sizes, int n_in,
                              void* d_out, int out_size, void* d_ws, size_t ws_size,
                              hipStream_t stream) {
  const float* x   = (const float*)d_in[0];
  const float* z   = (const float*)d_in[1];
  const float* lxg = (const float*)d_in[2];
  const float* lxb = (const float*)d_in[3];
  const float* lzg = (const float*)d_in[4];
  const float* lzb = (const float*)d_in[5];
  const float* Wq  = (const float*)d_in[6];
  const float* Wk  = (const float*)d_in[7];
  const float* Wv  = (const float*)d_in[8];
  const float* Wz  = (const float*)d_in[9];
  const float* Wo  = (const float*)d_in[10];
  const float* bo  = (const float*)d_in[11];

  char* ws = (char*)d_ws;
  unsigned short* xm  = (unsigned short*)(ws);
  unsigned short* qb  = (unsigned short*)(ws + 8388608);
  unsigned short* kb  = (unsigned short*)(ws + 16777216);
  unsigned short* vt  = (unsigned short*)(ws + 25165824);
  unsigned short* ao  = (unsigned short*)(ws + 33554432);
  unsigned short* wqt = (unsigned short*)(ws + 41943040);
  unsigned short* wkt = (unsigned short*)(ws + 42467328);
  unsigned short* wvt = (unsigned short*)(ws + 42991616);
  unsigned short* wot = (unsigned short*)(ws + 43515904);
  float*          z12 = (float*)(ws + 44040192);

  zpath_kernel<<<NBATCH, 256, 0, stream>>>(z, lzg, lzb, Wz, z12);
  xmod_kernel<<<NROWS / 4, 256, 0, stream>>>(x, lxg, lxb, z12, xm);
  wtrans_kernel<<<1024, 256, 0, stream>>>(Wq, wqt);
  wtrans_kernel<<<1024, 256, 0, stream>>>(Wk, wkt);
  wtrans_kernel<<<1024, 256, 0, stream>>>(Wv, wvt);
  wtrans_kernel<<<1024, 256, 0, stream>>>(Wo, wot);
  gemm_kernel<0><<<1024, 256, 0, stream>>>(xm, wqt, qb, nullptr);
  gemm_kernel<0><<<1024, 256, 0, stream>>>(xm, wkt, kb, nullptr);
  gemm_kernel<1><<<1024, 256, 0, stream>>>(xm, wvt, vt, nullptr);
  attn_kernel<<<1024, 256, 0, stream>>>(qb, kb, vt, ao);
  gemm_kernel<2><<<1024, 256, 0, stream>>>(ao, wot, d_out, bo);
}

// Round 2
// 297.799 us; speedup vs baseline: 1.3788x; 1.3788x over previous
//
#include <hip/hip_runtime.h>

#define XD 512
#define HEADS 8
#define DH 64
#define NSEQ 2048
#define NBATCH 4
#define NROWS (NBATCH*NSEQ)   // 8192

typedef __attribute__((ext_vector_type(8))) short bf16x8;
typedef __attribute__((ext_vector_type(8))) unsigned short u16x8;
typedef __attribute__((ext_vector_type(4))) float f32x4;

__device__ __forceinline__ unsigned short f2bf(float f) {
  union { float f; unsigned u; } v; v.f = f;
  return (unsigned short)((v.u + 0x7fffu + ((v.u >> 16) & 1u)) >> 16);
}

__device__ __forceinline__ float fexp2(float x) {
#if __has_builtin(__builtin_amdgcn_exp2f)
  return __builtin_amdgcn_exp2f(x);
#else
  return exp2f(x);
#endif
}

__device__ __forceinline__ unsigned cvt_pk_bf16(float lo, float hi) {
  unsigned r;
  asm("v_cvt_pk_bf16_f32 %0, %1, %2" : "=v"(r) : "v"(lo), "v"(hi));
  return r;
}

// ---------------- z path: LN(z) @ Wz -> silu -> z1,z2  (tiny) ----------------
__global__ __launch_bounds__(256) void zpath_kernel(
    const float* __restrict__ z, const float* __restrict__ g, const float* __restrict__ b,
    const float* __restrict__ Wz, float* __restrict__ z12) {
  int bb = blockIdx.x;            // batch
  int t = threadIdx.x;
  float zv[16];
  float mean = 0.f;
#pragma unroll
  for (int i = 0; i < 16; ++i) { zv[i] = z[bb * 16 + i]; mean += zv[i]; }
  mean *= (1.f / 16.f);
  float var = 0.f;
#pragma unroll
  for (int i = 0; i < 16; ++i) { float d = zv[i] - mean; var += d * d; }
  var *= (1.f / 16.f);
  float rs = rsqrtf(var + 1e-5f);
  float zn[16];
#pragma unroll
  for (int i = 0; i < 16; ++i) zn[i] = (zv[i] - mean) * rs * g[i] + b[i];
  for (int c = t; c < 1024; c += 256) {
    float acc = 0.f;
#pragma unroll
    for (int i = 0; i < 16; ++i) acc += zn[i] * Wz[i * 1024 + c];
    float s = acc / (1.f + __expf(-acc));   // silu
    z12[bb * 1024 + c] = s;
  }
}

// ---------------- x_mod = LN(x)*z1 + z2 -> bf16 [8192,512] ----------------
__global__ __launch_bounds__(256) void xmod_kernel(
    const float* __restrict__ x, const float* __restrict__ g, const float* __restrict__ b,
    const float* __restrict__ z12, unsigned short* __restrict__ xm) {
  int wave = threadIdx.x >> 6, lane = threadIdx.x & 63;
  int row = blockIdx.x * 4 + wave;
  const float* xr = x + (size_t)row * XD;
  float4 v0 = ((const float4*)xr)[lane * 2];
  float4 v1 = ((const float4*)xr)[lane * 2 + 1];
  float vv[8] = {v0.x, v0.y, v0.z, v0.w, v1.x, v1.y, v1.z, v1.w};
  float sum = 0.f, sq = 0.f;
#pragma unroll
  for (int i = 0; i < 8; ++i) { sum += vv[i]; sq += vv[i] * vv[i]; }
#pragma unroll
  for (int o = 32; o; o >>= 1) { sum += __shfl_xor(sum, o); sq += __shfl_xor(sq, o); }
  float mean = sum * (1.f / 512.f);
  float var = sq * (1.f / 512.f) - mean * mean;
  float rs = rsqrtf(var + 1e-5f);
  int bb = row >> 11;
  const float* zz = z12 + bb * 1024;
  int c0 = lane * 8;
  u16x8 o8;
#pragma unroll
  for (int i = 0; i < 8; ++i) {
    int c = c0 + i;
    float t = (vv[i] - mean) * rs * g[c] + b[c];
    t = t * zz[c] + zz[512 + c];
    o8[i] = f2bf(t);
  }
  *(u16x8*)(xm + (size_t)row * XD + c0) = o8;
}

// ---------------- weight transpose fp32[K,N] -> bf16 Wt[n*512+k] ----------------
__global__ __launch_bounds__(256) void wtrans_kernel(
    const float* __restrict__ W, unsigned short* __restrict__ Wt) {
  int idx = blockIdx.x * 256 + threadIdx.x;   // 0..262143 ; idx = n*512 + k
  int n = idx >> 9, k = idx & 511;
  Wt[idx] = f2bf(W[k * 512 + n]);
}

// ---------------- GEMM: C[8192,512] = A_bf16 @ W (Wt is [n][k] bf16) ----------------
// MODE 0: bf16 row-major out; MODE 1: per-head-transposed+slot-permuted V out;
// MODE 2: fp32 out + bias
template <int MODE>
__global__ __launch_bounds__(256) void gemm_kernel(
    const unsigned short* __restrict__ A, const unsigned short* __restrict__ Wt,
    void* __restrict__ out, const float* __restrict__ bias) {
  int wid = blockIdx.x * 4 + (threadIdx.x >> 6);
  int lane = threadIdx.x & 63;
  int nt = wid & 7, mt = wid >> 3;              // nt: 0..7 (64-col tile), mt: 0..511
  int lr = lane & 15, lg = lane >> 4;
  const size_t a_base = (size_t)(mt * 16 + lr) * 512 + lg * 8;
  f32x4 acc[4] = {};
  for (int kc = 0; kc < 512; kc += 32) {
    bf16x8 a = *(const bf16x8*)(A + a_base + kc);
#pragma unroll
    for (int ns = 0; ns < 4; ++ns) {
      int col = nt * 64 + ns * 16 + lr;
      bf16x8 bf = *(const bf16x8*)(Wt + (size_t)col * 512 + kc + lg * 8);
      acc[ns] = __builtin_amdgcn_mfma_f32_16x16x32_bf16(a, bf, acc[ns], 0, 0, 0);
    }
  }
#pragma unroll
  for (int ns = 0; ns < 4; ++ns) {
    int col = nt * 64 + ns * 16 + lr;
#pragma unroll
    for (int j = 0; j < 4; ++j) {
      int row = mt * 16 + lg * 4 + j;
      float v = acc[ns][j];
      if (MODE == 0) {
        ((unsigned short*)out)[(size_t)row * 512 + col] = f2bf(v);
      } else if (MODE == 1) {
        int bb = row >> 11, n = row & 2047, h = col >> 6, d = col & 63;
        // key-slot permutation within each 32-key block so that attn's
        // post-softmax P (packed straight from the QK^T C-layout) is a
        // valid 16x16x32 B-fragment:  slot(lg,kt,r) = lg*8 + kt*4 + r
        int j5 = n & 31;
        int slot = ((j5 >> 2) & 3) * 8 + ((j5 >> 4) & 1) * 4 + (j5 & 3);
        int np = (n & ~31) | slot;
        ((unsigned short*)out)[(((size_t)(bb * HEADS + h) * DH + d) << 11) + np] = f2bf(v);
      } else {
        ((float*)out)[(size_t)row * 512 + col] = v + bias[col];
      }
    }
  }
}

// ---------------- flash attention, swapped-QK / permuted-V, no LDS ----------------
// wave handles 32 q-rows of one (b,h); grid 512 blocks x 4 waves = 2048 waves
#define QB_PER_BH 64          // 2048/32
#define SCALE_L2E 0.18033688011112042f   // 0.125 * log2(e)
#define DEFER_THR 4.0f

__global__ __launch_bounds__(256) void attn_kernel(
    const unsigned short* __restrict__ Q, const unsigned short* __restrict__ K,
    const unsigned short* __restrict__ VT, unsigned short* __restrict__ O) {
  int widx = threadIdx.x >> 6, lane = threadIdx.x & 63;
  // XCD-aware swizzle: each XCD (blocks b with b&7 == x) owns 4 (b,h) pairs.
  int blk = blockIdx.x;
  int xcd = blk & 7;
  int idx = blk >> 3;                 // 0..63 within XCD
  int bh = xcd * 4 + (idx >> 4);      // 0..31
  int qb = (idx & 15) * 4 + widx;     // 0..63
  int b = bh >> 3, h = bh & 7;
  int lr = lane & 15, lg = lane >> 4;

  const size_t qk_base = (size_t)b * NSEQ * 512 + h * 64 + lg * 8;
  // Q fragments: 2 q-tiles x 2 d-halves
  bf16x8 qf[2][2];
#pragma unroll
  for (int qt = 0; qt < 2; ++qt) {
    size_t qa = qk_base + (size_t)(qb * 32 + qt * 16 + lr) * 512;
    qf[qt][0] = *(const bf16x8*)(Q + qa);
    qf[qt][1] = *(const bf16x8*)(Q + qa + 32);
  }
  const size_t vt_base = ((size_t)bh * DH + lr) * (size_t)NSEQ + lg * 8;

  float m[2] = {-3.0e38f, -3.0e38f};
  float l[2] = {0.f, 0.f};
  f32x4 o[2][4] = {};

  for (int kc = 0; kc < NSEQ; kc += 32) {
    // K fragments (A operand): rows = keys, contraction = d
    bf16x8 kf[2][2];
#pragma unroll
    for (int kt = 0; kt < 2; ++kt) {
      size_t ka = qk_base + (size_t)(kc + kt * 16 + lr) * 512;
      kf[kt][0] = *(const bf16x8*)(K + ka);
      kf[kt][1] = *(const bf16x8*)(K + ka + 32);
    }
    // V fragments (A operand for PV): rows = d, contraction = key-slot (pre-permuted)
    bf16x8 vf[4];
#pragma unroll
    for (int dt = 0; dt < 4; ++dt)
      vf[dt] = *(const bf16x8*)(VT + vt_base + (size_t)(dt * 16) * NSEQ + kc);

    // S^T = K·Q^T : lane holds col q = lane&15, rows k = lg*4+j (+16 per kt)
    f32x4 s[2][2] = {};
#pragma unroll
    for (int qt = 0; qt < 2; ++qt)
#pragma unroll
      for (int kt = 0; kt < 2; ++kt) {
        s[qt][kt] = __builtin_amdgcn_mfma_f32_16x16x32_bf16(kf[kt][0], qf[qt][0], s[qt][kt], 0, 0, 0);
        s[qt][kt] = __builtin_amdgcn_mfma_f32_16x16x32_bf16(kf[kt][1], qf[qt][1], s[qt][kt], 0, 0, 0);
      }

    float t[2][8], mx[2];
#pragma unroll
    for (int qt = 0; qt < 2; ++qt) {
#pragma unroll
      for (int kt = 0; kt < 2; ++kt)
#pragma unroll
        for (int j = 0; j < 4; ++j) t[qt][kt * 4 + j] = s[qt][kt][j] * SCALE_L2E;
      float m8 = t[qt][0];
#pragma unroll
      for (int i = 1; i < 8; ++i) m8 = fmaxf(m8, t[qt][i]);
      m8 = fmaxf(m8, __shfl_xor(m8, 16));
      m8 = fmaxf(m8, __shfl_xor(m8, 32));
      mx[qt] = m8;
    }
    // defer-max: only rescale when a row max grew by > DEFER_THR (exact math,
    // P values stay bounded by 2^DEFER_THR = 16)
    bool grow = (mx[0] > m[0] + DEFER_THR) || (mx[1] > m[1] + DEFER_THR);
    if (__any((int)grow)) {
#pragma unroll
      for (int qt = 0; qt < 2; ++qt) {
        float mn = fmaxf(m[qt], mx[qt]);
        float al = fexp2(m[qt] - mn);
        m[qt] = mn;
        l[qt] *= al;
#pragma unroll
        for (int dt = 0; dt < 4; ++dt)
#pragma unroll
          for (int j = 0; j < 4; ++j) o[qt][dt][j] *= al;
      }
    }
#pragma unroll
    for (int qt = 0; qt < 2; ++qt) {
      float p[8]; float rs = 0.f;
#pragma unroll
      for (int i = 0; i < 8; ++i) { p[i] = fexp2(t[qt][i] - m[qt]); rs += p[i]; }
      rs += __shfl_xor(rs, 16);
      rs += __shfl_xor(rs, 32);
      l[qt] += rs;
      union { unsigned w[4]; bf16x8 v; } pf;
#pragma unroll
      for (int d2 = 0; d2 < 4; ++d2) pf.w[d2] = cvt_pk_bf16(p[d2 * 2], p[d2 * 2 + 1]);
#pragma unroll
      for (int dt = 0; dt < 4; ++dt)
        o[qt][dt] = __builtin_amdgcn_mfma_f32_16x16x32_bf16(vf[dt], pf.v, o[qt][dt], 0, 0, 0);
    }
  }

#pragma unroll
  for (int qt = 0; qt < 2; ++qt) {
    float inv = 1.f / l[qt];
    size_t row = (size_t)(b * NSEQ + qb * 32 + qt * 16 + lr) * 512 + h * 64 + lg * 4;
#pragma unroll
    for (int dt = 0; dt < 4; ++dt) {
      unsigned w0 = cvt_pk_bf16(o[qt][dt][0] * inv, o[qt][dt][1] * inv);
      unsigned w1 = cvt_pk_bf16(o[qt][dt][2] * inv, o[qt][dt][3] * inv);
      uint2 st = {w0, w1};
      *(uint2*)(O + row + dt * 16) = st;
    }
  }
}

extern "C" void kernel_launch(void* const* d_in, const int* in_sizes, int n_in,
                              void* d_out, int out_size, void* d_ws, size_t ws_size,
                              hipStream_t stream) {
  const float* x   = (const float*)d_in[0];
  const float* z   = (const float*)d_in[1];
  const float* lxg = (const float*)d_in[2];
  const float* lxb = (const float*)d_in[3];
  const float* lzg = (const float*)d_in[4];
  const float* lzb = (const float*)d_in[5];
  const float* Wq  = (const float*)d_in[6];
  const float* Wk  = (const float*)d_in[7];
  const float* Wv  = (const float*)d_in[8];
  const float* Wz  = (const float*)d_in[9];
  const float* Wo  = (const float*)d_in[10];
  const float* bo  = (const float*)d_in[11];

  char* ws = (char*)d_ws;
  unsigned short* xm  = (unsigned short*)(ws);
  unsigned short* qb  = (unsigned short*)(ws + 8388608);
  unsigned short* kb  = (unsigned short*)(ws + 16777216);
  unsigned short* vt  = (unsigned short*)(ws + 25165824);
  unsigned short* ao  = (unsigned short*)(ws + 33554432);
  unsigned short* wqt = (unsigned short*)(ws + 41943040);
  unsigned short* wkt = (unsigned short*)(ws + 42467328);
  unsigned short* wvt = (unsigned short*)(ws + 42991616);
  unsigned short* wot = (unsigned short*)(ws + 43515904);
  float*          z12 = (float*)(ws + 44040192);

  zpath_kernel<<<NBATCH, 256, 0, stream>>>(z, lzg, lzb, Wz, z12);
  xmod_kernel<<<NROWS / 4, 256, 0, stream>>>(x, lxg, lxb, z12, xm);
  wtrans_kernel<<<1024, 256, 0, stream>>>(Wq, wqt);
  wtrans_kernel<<<1024, 256, 0, stream>>>(Wk, wkt);
  wtrans_kernel<<<1024, 256, 0, stream>>>(Wv, wvt);
  wtrans_kernel<<<1024, 256, 0, stream>>>(Wo, wot);
  gemm_kernel<0><<<1024, 256, 0, stream>>>(xm, wqt, qb, nullptr);
  gemm_kernel<0><<<1024, 256, 0, stream>>>(xm, wkt, kb, nullptr);
  gemm_kernel<1><<<1024, 256, 0, stream>>>(xm, wvt, vt, nullptr);
  attn_kernel<<<512, 256, 0, stream>>>(qb, kb, vt, ao);
  gemm_kernel<2><<<1024, 256, 0, stream>>>(ao, wot, d_out, bo);
}

// Round 4
// 293.807 us; speedup vs baseline: 1.3975x; 1.0136x over previous
//
#include <hip/hip_runtime.h>

#define XD 512
#define HEADS 8
#define DH 64
#define NSEQ 2048
#define NBATCH 4
#define NROWS (NBATCH*NSEQ)   // 8192

#define SCALE_L2E 0.18033688011112042f   // 0.125 * log2(e)
#define DEFER_THR 4.0f

typedef __attribute__((ext_vector_type(8))) short bf16x8;
typedef __attribute__((ext_vector_type(8))) unsigned short u16x8;
typedef __attribute__((ext_vector_type(4))) float f32x4;

__device__ __forceinline__ unsigned short f2bf(float f) {
  union { float f; unsigned u; } v; v.f = f;
  return (unsigned short)((v.u + 0x7fffu + ((v.u >> 16) & 1u)) >> 16);
}

__device__ __forceinline__ float fexp2(float x) {
#if __has_builtin(__builtin_amdgcn_exp2f)
  return __builtin_amdgcn_exp2f(x);
#else
  return exp2f(x);
#endif
}

__device__ __forceinline__ unsigned cvt_pk_bf16(float lo, float hi) {
  unsigned r;
  asm("v_cvt_pk_bf16_f32 %0, %1, %2" : "=v"(r) : "v"(lo), "v"(hi));
  return r;
}

// ---------------- z path: LN(z) @ Wz -> silu -> z1,z2  (tiny) ----------------
__global__ __launch_bounds__(256) void zpath_kernel(
    const float* __restrict__ z, const float* __restrict__ g, const float* __restrict__ b,
    const float* __restrict__ Wz, float* __restrict__ z12) {
  int bb = blockIdx.x;            // batch
  int t = threadIdx.x;
  float zv[16];
  float mean = 0.f;
#pragma unroll
  for (int i = 0; i < 16; ++i) { zv[i] = z[bb * 16 + i]; mean += zv[i]; }
  mean *= (1.f / 16.f);
  float var = 0.f;
#pragma unroll
  for (int i = 0; i < 16; ++i) { float d = zv[i] - mean; var += d * d; }
  var *= (1.f / 16.f);
  float rs = rsqrtf(var + 1e-5f);
  float zn[16];
#pragma unroll
  for (int i = 0; i < 16; ++i) zn[i] = (zv[i] - mean) * rs * g[i] + b[i];
  for (int c = t; c < 1024; c += 256) {
    float acc = 0.f;
#pragma unroll
    for (int i = 0; i < 16; ++i) acc += zn[i] * Wz[i * 1024 + c];
    float s = acc / (1.f + __expf(-acc));   // silu
    z12[bb * 1024 + c] = s;
  }
}

// ---------------- x_mod = LN(x)*z1 + z2 -> bf16 [8192,512] ----------------
__global__ __launch_bounds__(256) void xmod_kernel(
    const float* __restrict__ x, const float* __restrict__ g, const float* __restrict__ b,
    const float* __restrict__ z12, unsigned short* __restrict__ xm) {
  int wave = threadIdx.x >> 6, lane = threadIdx.x & 63;
  int row = blockIdx.x * 4 + wave;
  const float* xr = x + (size_t)row * XD;
  float4 v0 = ((const float4*)xr)[lane * 2];
  float4 v1 = ((const float4*)xr)[lane * 2 + 1];
  float vv[8] = {v0.x, v0.y, v0.z, v0.w, v1.x, v1.y, v1.z, v1.w};
  float sum = 0.f, sq = 0.f;
#pragma unroll
  for (int i = 0; i < 8; ++i) { sum += vv[i]; sq += vv[i] * vv[i]; }
#pragma unroll
  for (int o = 32; o; o >>= 1) { sum += __shfl_xor(sum, o); sq += __shfl_xor(sq, o); }
  float mean = sum * (1.f / 512.f);
  float var = sq * (1.f / 512.f) - mean * mean;
  float rs = rsqrtf(var + 1e-5f);
  int bb = row >> 11;
  const float* zz = z12 + bb * 1024;
  int c0 = lane * 8;
  u16x8 o8;
#pragma unroll
  for (int i = 0; i < 8; ++i) {
    int c = c0 + i;
    float t = (vv[i] - mean) * rs * g[c] + b[c];
    t = t * zz[c] + zz[512 + c];
    o8[i] = f2bf(t);
  }
  *(u16x8*)(xm + (size_t)row * XD + c0) = o8;
}

// ------- fused weight transpose fp32[K,N] -> bf16 [n][k] for Wq,Wk,Wv,Wo -------
__global__ __launch_bounds__(256) void wtrans4_kernel(
    const float* __restrict__ W0, const float* __restrict__ W1,
    const float* __restrict__ W2, const float* __restrict__ W3,
    unsigned short* __restrict__ dst) {
  int idx = blockIdx.x * 256 + threadIdx.x;   // 0..1048575
  int w = idx >> 18;                           // which weight (block-uniform)
  int e = idx & 262143;                        // n*512 + k
  int n = e >> 9, k = e & 511;
  const float* W = (w == 0) ? W0 : (w == 1) ? W1 : (w == 2) ? W2 : W3;
  dst[idx] = f2bf(W[k * 512 + n]);
}

// ---------------- GEMM: C[8192,512] = A_bf16 @ W (Wt is [n][k] bf16) ----------------
// MODE 0: bf16 row-major out; MODE 1: per-head-transposed+slot-permuted V out;
// MODE 2: fp32 out + bias
template <int MODE>
__global__ __launch_bounds__(256) void gemm_kernel(
    const unsigned short* __restrict__ A, const unsigned short* __restrict__ Wt,
    void* __restrict__ out, const float* __restrict__ bias) {
  int wid = blockIdx.x * 4 + (threadIdx.x >> 6);
  int lane = threadIdx.x & 63;
  int nt = wid & 7, mt = wid >> 3;              // nt: 0..7 (64-col tile), mt: 0..511
  int lr = lane & 15, lg = lane >> 4;
  const size_t a_base = (size_t)(mt * 16 + lr) * 512 + lg * 8;
  f32x4 acc[4] = {};
  for (int kc = 0; kc < 512; kc += 32) {
    bf16x8 a = *(const bf16x8*)(A + a_base + kc);
#pragma unroll
    for (int ns = 0; ns < 4; ++ns) {
      int col = nt * 64 + ns * 16 + lr;
      bf16x8 bf = *(const bf16x8*)(Wt + (size_t)col * 512 + kc + lg * 8);
      acc[ns] = __builtin_amdgcn_mfma_f32_16x16x32_bf16(a, bf, acc[ns], 0, 0, 0);
    }
  }
#pragma unroll
  for (int ns = 0; ns < 4; ++ns) {
    int col = nt * 64 + ns * 16 + lr;
#pragma unroll
    for (int j = 0; j < 4; ++j) {
      int row = mt * 16 + lg * 4 + j;
      float v = acc[ns][j];
      if (MODE == 0) {
        ((unsigned short*)out)[(size_t)row * 512 + col] = f2bf(v);
      } else if (MODE == 1) {
        int bb = row >> 11, n = row & 2047, h = col >> 6, d = col & 63;
        // key-slot permutation within each 32-key block so that attn's
        // post-softmax P (packed straight from the QK^T C-layout) is a
        // valid 16x16x32 B-fragment:  slot(lg,kt,r) = lg*8 + kt*4 + r
        int j5 = n & 31;
        int slot = ((j5 >> 2) & 3) * 8 + ((j5 >> 4) & 1) * 4 + (j5 & 3);
        int np = (n & ~31) | slot;
        ((unsigned short*)out)[(((size_t)(bb * HEADS + h) * DH + d) << 11) + np] = f2bf(v);
      } else {
        ((float*)out)[(size_t)row * 512 + col] = v + bias[col];
      }
    }
  }
}

// ---------------- flash attention, swapped-QK / permuted-V, no LDS ----------------
// wave = 32 q-rows of one (b,h); straight-line register double-buffer, clamped tail.
// __launch_bounds__(256,2): grid is exactly 2 blocks/CU, allow up to 256 VGPR.

#define LOADKV(kf, vf, kcc) do {                                          \
    _Pragma("unroll")                                                     \
    for (int kt = 0; kt < 2; ++kt) {                                      \
      const unsigned short* ka = Kp + (size_t)((kcc) + kt * 16) * 512;    \
      kf[kt][0] = *(const bf16x8*)(ka);                                   \
      kf[kt][1] = *(const bf16x8*)(ka + 32);                              \
    }                                                                     \
    _Pragma("unroll")                                                     \
    for (int dt = 0; dt < 4; ++dt)                                        \
      vf[dt] = *(const bf16x8*)(Vp + (size_t)(dt * 16) * NSEQ + (kcc));   \
  } while (0)

// verbatim R2-passing math: scale applied here, defer-max, cvt_pk pack
#define PROCESS(kf, vf) do {                                              \
    f32x4 s[2][2] = {};                                                   \
    _Pragma("unroll")                                                     \
    for (int qt = 0; qt < 2; ++qt)                                        \
      _Pragma("unroll")                                                   \
      for (int kt = 0; kt < 2; ++kt) {                                    \
        s[qt][kt] = __builtin_amdgcn_mfma_f32_16x16x32_bf16(kf[kt][0], qf[qt][0], s[qt][kt], 0, 0, 0); \
        s[qt][kt] = __builtin_amdgcn_mfma_f32_16x16x32_bf16(kf[kt][1], qf[qt][1], s[qt][kt], 0, 0, 0); \
      }                                                                   \
    float t[2][8], mx[2];                                                 \
    _Pragma("unroll")                                                     \
    for (int qt = 0; qt < 2; ++qt) {                                      \
      _Pragma("unroll")                                                   \
      for (int kt = 0; kt < 2; ++kt)                                      \
        _Pragma("unroll")                                                 \
        for (int j = 0; j < 4; ++j) t[qt][kt * 4 + j] = s[qt][kt][j] * SCALE_L2E; \
      float m8 = t[qt][0];                                                \
      _Pragma("unroll")                                                   \
      for (int i = 1; i < 8; ++i) m8 = fmaxf(m8, t[qt][i]);               \
      m8 = fmaxf(m8, __shfl_xor(m8, 16));                                 \
      m8 = fmaxf(m8, __shfl_xor(m8, 32));                                 \
      mx[qt] = m8;                                                        \
    }                                                                     \
    bool grow = (mx[0] > m[0] + DEFER_THR) || (mx[1] > m[1] + DEFER_THR); \
    if (__any((int)grow)) {                                               \
      _Pragma("unroll")                                                   \
      for (int qt = 0; qt < 2; ++qt) {                                    \
        float mn = fmaxf(m[qt], mx[qt]);                                  \
        float al = fexp2(m[qt] - mn);                                     \
        m[qt] = mn;                                                       \
        l[qt] *= al;                                                      \
        _Pragma("unroll")                                                 \
        for (int dt = 0; dt < 4; ++dt)                                    \
          _Pragma("unroll")                                               \
          for (int j = 0; j < 4; ++j) o[qt][dt][j] *= al;                 \
      }                                                                   \
    }                                                                     \
    _Pragma("unroll")                                                     \
    for (int qt = 0; qt < 2; ++qt) {                                      \
      float p[8]; float rs = 0.f;                                         \
      _Pragma("unroll")                                                   \
      for (int i = 0; i < 8; ++i) { p[i] = fexp2(t[qt][i] - m[qt]); rs += p[i]; } \
      rs += __shfl_xor(rs, 16);                                           \
      rs += __shfl_xor(rs, 32);                                           \
      l[qt] += rs;                                                        \
      union { unsigned w[4]; bf16x8 v; } pf;                              \
      _Pragma("unroll")                                                   \
      for (int d2 = 0; d2 < 4; ++d2) pf.w[d2] = cvt_pk_bf16(p[d2 * 2], p[d2 * 2 + 1]); \
      _Pragma("unroll")                                                   \
      for (int dt = 0; dt < 4; ++dt)                                      \
        o[qt][dt] = __builtin_amdgcn_mfma_f32_16x16x32_bf16(vf[dt], pf.v, o[qt][dt], 0, 0, 0); \
    }                                                                     \
  } while (0)

__global__ __launch_bounds__(256, 2) void attn_kernel(
    const unsigned short* __restrict__ Q, const unsigned short* __restrict__ K,
    const unsigned short* __restrict__ VT, unsigned short* __restrict__ O) {
  int widx = threadIdx.x >> 6, lane = threadIdx.x & 63;
  // XCD-aware swizzle: each XCD (blocks b with b&7 == x) owns 4 (b,h) pairs.
  int blk = blockIdx.x;
  int xcd = blk & 7;
  int idx = blk >> 3;                 // 0..63 within XCD
  int bh = xcd * 4 + (idx >> 4);      // 0..31
  int qb = (idx & 15) * 4 + widx;     // 0..63
  int b = bh >> 3, h = bh & 7;
  int lr = lane & 15, lg = lane >> 4;

  const size_t qk_base = (size_t)b * NSEQ * 512 + h * 64 + lg * 8;
  bf16x8 qf[2][2];
#pragma unroll
  for (int qt = 0; qt < 2; ++qt) {
    size_t qa = qk_base + (size_t)(qb * 32 + qt * 16 + lr) * 512;
    qf[qt][0] = *(const bf16x8*)(Q + qa);
    qf[qt][1] = *(const bf16x8*)(Q + qa + 32);
  }
  const unsigned short* Kp = K + qk_base + (size_t)lr * 512;
  const unsigned short* Vp = VT + ((size_t)bh * DH + lr) * (size_t)NSEQ + lg * 8;

  float m[2] = {-3.0e38f, -3.0e38f};
  float l[2] = {0.f, 0.f};
  f32x4 o[2][4] = {};

  bf16x8 kfA[2][2], vfA[4], kfB[2][2], vfB[4];

  LOADKV(kfA, vfA, 0);
  for (int kc = 0; kc < NSEQ; kc += 64) {
    LOADKV(kfB, vfB, kc + 32);
    PROCESS(kfA, vfA);
    // clamped tail: on the last iteration reload chunk 0 (valid, discarded)
    int kn = (kc + 64 < NSEQ) ? (kc + 64) : 0;
    LOADKV(kfA, vfA, kn);
    PROCESS(kfB, vfB);
  }

#pragma unroll
  for (int qt = 0; qt < 2; ++qt) {
    float inv = 1.f / l[qt];
    size_t row = (size_t)(b * NSEQ + qb * 32 + qt * 16 + lr) * 512 + h * 64 + lg * 4;
#pragma unroll
    for (int dt = 0; dt < 4; ++dt) {
      unsigned w0 = cvt_pk_bf16(o[qt][dt][0] * inv, o[qt][dt][1] * inv);
      unsigned w1 = cvt_pk_bf16(o[qt][dt][2] * inv, o[qt][dt][3] * inv);
      uint2 st = {w0, w1};
      *(uint2*)(O + row + dt * 16) = st;
    }
  }
}

extern "C" void kernel_launch(void* const* d_in, const int* in_sizes, int n_in,
                              void* d_out, int out_size, void* d_ws, size_t ws_size,
                              hipStream_t stream) {
  const float* x   = (const float*)d_in[0];
  const float* z   = (const float*)d_in[1];
  const float* lxg = (const float*)d_in[2];
  const float* lxb = (const float*)d_in[3];
  const float* lzg = (const float*)d_in[4];
  const float* lzb = (const float*)d_in[5];
  const float* Wq  = (const float*)d_in[6];
  const float* Wk  = (const float*)d_in[7];
  const float* Wv  = (const float*)d_in[8];
  const float* Wz  = (const float*)d_in[9];
  const float* Wo  = (const float*)d_in[10];
  const float* bo  = (const float*)d_in[11];

  char* ws = (char*)d_ws;
  unsigned short* xm  = (unsigned short*)(ws);
  unsigned short* qb  = (unsigned short*)(ws + 8388608);
  unsigned short* kb  = (unsigned short*)(ws + 16777216);
  unsigned short* vt  = (unsigned short*)(ws + 25165824);
  unsigned short* ao  = (unsigned short*)(ws + 33554432);
  unsigned short* wqt = (unsigned short*)(ws + 41943040);   // wq,wk,wv,wo contiguous
  unsigned short* wkt = (unsigned short*)(ws + 42467328);
  unsigned short* wvt = (unsigned short*)(ws + 42991616);
  unsigned short* wot = (unsigned short*)(ws + 43515904);
  float*          z12 = (float*)(ws + 44040192);

  zpath_kernel<<<NBATCH, 256, 0, stream>>>(z, lzg, lzb, Wz, z12);
  xmod_kernel<<<NROWS / 4, 256, 0, stream>>>(x, lxg, lxb, z12, xm);
  wtrans4_kernel<<<4096, 256, 0, stream>>>(Wq, Wk, Wv, Wo, wqt);
  gemm_kernel<0><<<1024, 256, 0, stream>>>(xm, wqt, qb, nullptr);
  gemm_kernel<0><<<1024, 256, 0, stream>>>(xm, wkt, kb, nullptr);
  gemm_kernel<1><<<1024, 256, 0, stream>>>(xm, wvt, vt, nullptr);
  attn_kernel<<<512, 256, 0, stream>>>(qb, kb, vt, ao);
  gemm_kernel<2><<<1024, 256, 0, stream>>>(ao, wot, d_out, bo);
}

// Round 5
// 196.367 us; speedup vs baseline: 2.0909x; 1.4962x over previous
//
#include <hip/hip_runtime.h>

#define XD 512
#define HEADS 8
#define DH 64
#define NSEQ 2048
#define NBATCH 4
#define NROWS (NBATCH*NSEQ)   // 8192

#define SCALE_L2E 0.18033688011112042f   // 0.125 * log2(e)
#define DEFER_THR 4.0f

typedef __attribute__((ext_vector_type(8))) short bf16x8;
typedef __attribute__((ext_vector_type(8))) unsigned short u16x8;
typedef __attribute__((ext_vector_type(4))) float f32x4;

__device__ __forceinline__ unsigned short f2bf(float f) {
  union { float f; unsigned u; } v; v.f = f;
  return (unsigned short)((v.u + 0x7fffu + ((v.u >> 16) & 1u)) >> 16);
}

__device__ __forceinline__ float fexp2(float x) {
#if __has_builtin(__builtin_amdgcn_exp2f)
  return __builtin_amdgcn_exp2f(x);
#else
  return exp2f(x);
#endif
}

__device__ __forceinline__ unsigned cvt_pk_bf16(float lo, float hi) {
  unsigned r;
  asm("v_cvt_pk_bf16_f32 %0, %1, %2" : "=v"(r) : "v"(lo), "v"(hi));
  return r;
}

// async global->LDS, 16B per lane; LDS dest must be wave-uniform base (HW adds lane*16)
__device__ __forceinline__ void gload_lds16(const unsigned short* g, unsigned short* l) {
  __builtin_amdgcn_global_load_lds(
      (const __attribute__((address_space(1))) unsigned int*)g,
      (__attribute__((address_space(3))) unsigned int*)l, 16, 0, 0);
}

// ---------------- z path: LN(z) @ Wz -> silu -> z1,z2  (tiny) ----------------
__global__ __launch_bounds__(256) void zpath_kernel(
    const float* __restrict__ z, const float* __restrict__ g, const float* __restrict__ b,
    const float* __restrict__ Wz, float* __restrict__ z12) {
  int bb = blockIdx.x;            // batch
  int t = threadIdx.x;
  float zv[16];
  float mean = 0.f;
#pragma unroll
  for (int i = 0; i < 16; ++i) { zv[i] = z[bb * 16 + i]; mean += zv[i]; }
  mean *= (1.f / 16.f);
  float var = 0.f;
#pragma unroll
  for (int i = 0; i < 16; ++i) { float d = zv[i] - mean; var += d * d; }
  var *= (1.f / 16.f);
  float rs = rsqrtf(var + 1e-5f);
  float zn[16];
#pragma unroll
  for (int i = 0; i < 16; ++i) zn[i] = (zv[i] - mean) * rs * g[i] + b[i];
  for (int c = t; c < 1024; c += 256) {
    float acc = 0.f;
#pragma unroll
    for (int i = 0; i < 16; ++i) acc += zn[i] * Wz[i * 1024 + c];
    float s = acc / (1.f + __expf(-acc));   // silu
    z12[bb * 1024 + c] = s;
  }
}

// ---------------- x_mod = LN(x)*z1 + z2 -> bf16 [8192,512] ----------------
__global__ __launch_bounds__(256) void xmod_kernel(
    const float* __restrict__ x, const float* __restrict__ g, const float* __restrict__ b,
    const float* __restrict__ z12, unsigned short* __restrict__ xm) {
  int wave = threadIdx.x >> 6, lane = threadIdx.x & 63;
  int row = blockIdx.x * 4 + wave;
  const float* xr = x + (size_t)row * XD;
  float4 v0 = ((const float4*)xr)[lane * 2];
  float4 v1 = ((const float4*)xr)[lane * 2 + 1];
  float vv[8] = {v0.x, v0.y, v0.z, v0.w, v1.x, v1.y, v1.z, v1.w};
  float sum = 0.f, sq = 0.f;
#pragma unroll
  for (int i = 0; i < 8; ++i) { sum += vv[i]; sq += vv[i] * vv[i]; }
#pragma unroll
  for (int o = 32; o; o >>= 1) { sum += __shfl_xor(sum, o); sq += __shfl_xor(sq, o); }
  float mean = sum * (1.f / 512.f);
  float var = sq * (1.f / 512.f) - mean * mean;
  float rs = rsqrtf(var + 1e-5f);
  int bb = row >> 11;
  const float* zz = z12 + bb * 1024;
  int c0 = lane * 8;
  u16x8 o8;
#pragma unroll
  for (int i = 0; i < 8; ++i) {
    int c = c0 + i;
    float t = (vv[i] - mean) * rs * g[c] + b[c];
    t = t * zz[c] + zz[512 + c];
    o8[i] = f2bf(t);
  }
  *(u16x8*)(xm + (size_t)row * XD + c0) = o8;
}

// ------- fused weight transpose fp32[K,N] -> bf16 [n][k] for Wq,Wk,Wv,Wo -------
__global__ __launch_bounds__(256) void wtrans4_kernel(
    const float* __restrict__ W0, const float* __restrict__ W1,
    const float* __restrict__ W2, const float* __restrict__ W3,
    unsigned short* __restrict__ dst) {
  int idx = blockIdx.x * 256 + threadIdx.x;   // 0..1048575
  int w = idx >> 18;                           // which weight (block-uniform)
  int e = idx & 262143;                        // n*512 + k
  int n = e >> 9, k = e & 511;
  const float* W = (w == 0) ? W0 : (w == 1) ? W1 : (w == 2) ? W2 : W3;
  dst[idx] = f2bf(W[k * 512 + n]);
}

// ---------- GEMM (m97-style): C[8192,512] = A_bf16 @ W, LDS-staged ----------
// BM=128, BN=64, BK=64; 256 threads = 4 waves (2 m-waves x 2 n-waves);
// per wave 64x32 output = 4x2 frags of 16x16. global_load_lds width-16 staging.
// MODE 0: bf16 row-major out; MODE 1: per-head-transposed+slot-permuted V out;
// MODE 2: fp32 out + bias
template <int MODE>
__global__ __launch_bounds__(256, 2) void gemm_kernel(
    const unsigned short* __restrict__ A, const unsigned short* __restrict__ Wt,
    void* __restrict__ out, const float* __restrict__ bias) {
  __shared__ unsigned short Alds[128 * 64];
  __shared__ unsigned short Blds[64 * 64];
  int widx = threadIdx.x >> 6, lane = threadIdx.x & 63;
  int blk = blockIdx.x;
  int nt = blk & 7, mt = blk >> 3;       // 8 n-tiles, 64 m-tiles
  int blkM = mt * 128, blkN = nt * 64;
  int wr = widx >> 1, wc = widx & 1;
  int lr = lane & 15, lg = lane >> 4;
  int srow = lane >> 3, scol = (lane & 7) * 8;   // staging: 8 rows/instr, 8 cols/lane

  const unsigned short* Ag = A + (size_t)(blkM + widx * 32 + srow) * 512 + scol;
  const unsigned short* Bg = Wt + (size_t)(blkN + widx * 16 + srow) * 512 + scol;
  unsigned short* Al = &Alds[(widx * 32) * 64];   // wave-uniform LDS bases
  unsigned short* Bl = &Blds[(widx * 16) * 64];

  f32x4 acc[4][2] = {};

  for (int kc = 0; kc < 512; kc += 64) {
    // stage A: 4 instrs x 8 rows; B: 2 instrs x 8 rows (per wave)
#pragma unroll
    for (int i = 0; i < 4; ++i)
      gload_lds16(Ag + (size_t)(i * 8) * 512 + kc, Al + (i * 8) * 64);
#pragma unroll
    for (int i = 0; i < 2; ++i)
      gload_lds16(Bg + (size_t)(i * 8) * 512 + kc, Bl + (i * 8) * 64);
    __syncthreads();   // drains global_load_lds (vmcnt0) + all waves staged

#pragma unroll
    for (int kh = 0; kh < 2; ++kh) {
      bf16x8 bfr[2];
#pragma unroll
      for (int ni = 0; ni < 2; ++ni)
        bfr[ni] = *(const bf16x8*)&Blds[(wc * 32 + ni * 16 + lr) * 64 + kh * 32 + lg * 8];
#pragma unroll
      for (int mi = 0; mi < 4; ++mi) {
        bf16x8 afr = *(const bf16x8*)&Alds[(wr * 64 + mi * 16 + lr) * 64 + kh * 32 + lg * 8];
#pragma unroll
        for (int ni = 0; ni < 2; ++ni)
          acc[mi][ni] = __builtin_amdgcn_mfma_f32_16x16x32_bf16(afr, bfr[ni], acc[mi][ni], 0, 0, 0);
      }
    }
    __syncthreads();   // protect LDS before next stage
  }

#pragma unroll
  for (int mi = 0; mi < 4; ++mi)
#pragma unroll
    for (int ni = 0; ni < 2; ++ni) {
      int col = blkN + wc * 32 + ni * 16 + lr;
#pragma unroll
      for (int j = 0; j < 4; ++j) {
        int row = blkM + wr * 64 + mi * 16 + lg * 4 + j;
        float v = acc[mi][ni][j];
        if (MODE == 0) {
          ((unsigned short*)out)[(size_t)row * 512 + col] = f2bf(v);
        } else if (MODE == 1) {
          int bb = row >> 11, n = row & 2047, h = col >> 6, d = col & 63;
          // key-slot permutation within each 32-key block so attn's post-softmax
          // P (packed straight from QK^T C-layout) is a valid 16x16x32 B-fragment
          int j5 = n & 31;
          int slot = ((j5 >> 2) & 3) * 8 + ((j5 >> 4) & 1) * 4 + (j5 & 3);
          int np = (n & ~31) | slot;
          ((unsigned short*)out)[(((size_t)(bb * HEADS + h) * DH + d) << 11) + np] = f2bf(v);
        } else {
          ((float*)out)[(size_t)row * 512 + col] = v + bias[col];
        }
      }
    }
}

// ---------------- flash attention, swapped-QK / permuted-V, no LDS ----------------
// (unchanged from R3-passing version)

#define LOADKV(kf, vf, kcc) do {                                          \
    _Pragma("unroll")                                                     \
    for (int kt = 0; kt < 2; ++kt) {                                      \
      const unsigned short* ka = Kp + (size_t)((kcc) + kt * 16) * 512;    \
      kf[kt][0] = *(const bf16x8*)(ka);                                   \
      kf[kt][1] = *(const bf16x8*)(ka + 32);                              \
    }                                                                     \
    _Pragma("unroll")                                                     \
    for (int dt = 0; dt < 4; ++dt)                                        \
      vf[dt] = *(const bf16x8*)(Vp + (size_t)(dt * 16) * NSEQ + (kcc));   \
  } while (0)

#define PROCESS(kf, vf) do {                                              \
    f32x4 s[2][2] = {};                                                   \
    _Pragma("unroll")                                                     \
    for (int qt = 0; qt < 2; ++qt)                                        \
      _Pragma("unroll")                                                   \
      for (int kt = 0; kt < 2; ++kt) {                                    \
        s[qt][kt] = __builtin_amdgcn_mfma_f32_16x16x32_bf16(kf[kt][0], qf[qt][0], s[qt][kt], 0, 0, 0); \
        s[qt][kt] = __builtin_amdgcn_mfma_f32_16x16x32_bf16(kf[kt][1], qf[qt][1], s[qt][kt], 0, 0, 0); \
      }                                                                   \
    float t[2][8], mx[2];                                                 \
    _Pragma("unroll")                                                     \
    for (int qt = 0; qt < 2; ++qt) {                                      \
      _Pragma("unroll")                                                   \
      for (int kt = 0; kt < 2; ++kt)                                      \
        _Pragma("unroll")                                                 \
        for (int j = 0; j < 4; ++j) t[qt][kt * 4 + j] = s[qt][kt][j] * SCALE_L2E; \
      float m8 = t[qt][0];                                                \
      _Pragma("unroll")                                                   \
      for (int i = 1; i < 8; ++i) m8 = fmaxf(m8, t[qt][i]);               \
      m8 = fmaxf(m8, __shfl_xor(m8, 16));                                 \
      m8 = fmaxf(m8, __shfl_xor(m8, 32));                                 \
      mx[qt] = m8;                                                        \
    }                                                                     \
    bool grow = (mx[0] > m[0] + DEFER_THR) || (mx[1] > m[1] + DEFER_THR); \
    if (__any((int)grow)) {                                               \
      _Pragma("unroll")                                                   \
      for (int qt = 0; qt < 2; ++qt) {                                    \
        float mn = fmaxf(m[qt], mx[qt]);                                  \
        float al = fexp2(m[qt] - mn);                                     \
        m[qt] = mn;                                                       \
        l[qt] *= al;                                                      \
        _Pragma("unroll")                                                 \
        for (int dt = 0; dt < 4; ++dt)                                    \
          _Pragma("unroll")                                               \
          for (int j = 0; j < 4; ++j) o[qt][dt][j] *= al;                 \
      }                                                                   \
    }                                                                     \
    _Pragma("unroll")                                                     \
    for (int qt = 0; qt < 2; ++qt) {                                      \
      float p[8]; float rs = 0.f;                                         \
      _Pragma("unroll")                                                   \
      for (int i = 0; i < 8; ++i) { p[i] = fexp2(t[qt][i] - m[qt]); rs += p[i]; } \
      rs += __shfl_xor(rs, 16);                                           \
      rs += __shfl_xor(rs, 32);                                           \
      l[qt] += rs;                                                        \
      union { unsigned w[4]; bf16x8 v; } pf;                              \
      _Pragma("unroll")                                                   \
      for (int d2 = 0; d2 < 4; ++d2) pf.w[d2] = cvt_pk_bf16(p[d2 * 2], p[d2 * 2 + 1]); \
      _Pragma("unroll")                                                   \
      for (int dt = 0; dt < 4; ++dt)                                      \
        o[qt][dt] = __builtin_amdgcn_mfma_f32_16x16x32_bf16(vf[dt], pf.v, o[qt][dt], 0, 0, 0); \
    }                                                                     \
  } while (0)

__global__ __launch_bounds__(256, 2) void attn_kernel(
    const unsigned short* __restrict__ Q, const unsigned short* __restrict__ K,
    const unsigned short* __restrict__ VT, unsigned short* __restrict__ O) {
  int widx = threadIdx.x >> 6, lane = threadIdx.x & 63;
  int blk = blockIdx.x;
  int xcd = blk & 7;
  int idx = blk >> 3;                 // 0..63 within XCD
  int bh = xcd * 4 + (idx >> 4);      // 0..31
  int qb = (idx & 15) * 4 + widx;     // 0..63
  int b = bh >> 3, h = bh & 7;
  int lr = lane & 15, lg = lane >> 4;

  const size_t qk_base = (size_t)b * NSEQ * 512 + h * 64 + lg * 8;
  bf16x8 qf[2][2];
#pragma unroll
  for (int qt = 0; qt < 2; ++qt) {
    size_t qa = qk_base + (size_t)(qb * 32 + qt * 16 + lr) * 512;
    qf[qt][0] = *(const bf16x8*)(Q + qa);
    qf[qt][1] = *(const bf16x8*)(Q + qa + 32);
  }
  const unsigned short* Kp = K + qk_base + (size_t)lr * 512;
  const unsigned short* Vp = VT + ((size_t)bh * DH + lr) * (size_t)NSEQ + lg * 8;

  float m[2] = {-3.0e38f, -3.0e38f};
  float l[2] = {0.f, 0.f};
  f32x4 o[2][4] = {};

  bf16x8 kfA[2][2], vfA[4], kfB[2][2], vfB[4];

  LOADKV(kfA, vfA, 0);
  for (int kc = 0; kc < NSEQ; kc += 64) {
    LOADKV(kfB, vfB, kc + 32);
    PROCESS(kfA, vfA);
    int kn = (kc + 64 < NSEQ) ? (kc + 64) : 0;
    LOADKV(kfA, vfA, kn);
    PROCESS(kfB, vfB);
  }

#pragma unroll
  for (int qt = 0; qt < 2; ++qt) {
    float inv = 1.f / l[qt];
    size_t row = (size_t)(b * NSEQ + qb * 32 + qt * 16 + lr) * 512 + h * 64 + lg * 4;
#pragma unroll
    for (int dt = 0; dt < 4; ++dt) {
      unsigned w0 = cvt_pk_bf16(o[qt][dt][0] * inv, o[qt][dt][1] * inv);
      unsigned w1 = cvt_pk_bf16(o[qt][dt][2] * inv, o[qt][dt][3] * inv);
      uint2 st = {w0, w1};
      *(uint2*)(O + row + dt * 16) = st;
    }
  }
}

extern "C" void kernel_launch(void* const* d_in, const int* in_sizes, int n_in,
                              void* d_out, int out_size, void* d_ws, size_t ws_size,
                              hipStream_t stream) {
  const float* x   = (const float*)d_in[0];
  const float* z   = (const float*)d_in[1];
  const float* lxg = (const float*)d_in[2];
  const float* lxb = (const float*)d_in[3];
  const float* lzg = (const float*)d_in[4];
  const float* lzb = (const float*)d_in[5];
  const float* Wq  = (const float*)d_in[6];
  const float* Wk  = (const float*)d_in[7];
  const float* Wv  = (const float*)d_in[8];
  const float* Wz  = (const float*)d_in[9];
  const float* Wo  = (const float*)d_in[10];
  const float* bo  = (const float*)d_in[11];

  char* ws = (char*)d_ws;
  unsigned short* xm  = (unsigned short*)(ws);
  unsigned short* qb  = (unsigned short*)(ws + 8388608);
  unsigned short* kb  = (unsigned short*)(ws + 16777216);
  unsigned short* vt  = (unsigned short*)(ws + 25165824);
  unsigned short* ao  = (unsigned short*)(ws + 33554432);
  unsigned short* wqt = (unsigned short*)(ws + 41943040);   // wq,wk,wv,wo contiguous
  unsigned short* wkt = (unsigned short*)(ws + 42467328);
  unsigned short* wvt = (unsigned short*)(ws + 42991616);
  unsigned short* wot = (unsigned short*)(ws + 43515904);
  float*          z12 = (float*)(ws + 44040192);

  zpath_kernel<<<NBATCH, 256, 0, stream>>>(z, lzg, lzb, Wz, z12);
  xmod_kernel<<<NROWS / 4, 256, 0, stream>>>(x, lxg, lxb, z12, xm);
  wtrans4_kernel<<<4096, 256, 0, stream>>>(Wq, Wk, Wv, Wo, wqt);
  gemm_kernel<0><<<512, 256, 0, stream>>>(xm, wqt, qb, nullptr);
  gemm_kernel<0><<<512, 256, 0, stream>>>(xm, wkt, kb, nullptr);
  gemm_kernel<1><<<512, 256, 0, stream>>>(xm, wvt, vt, nullptr);
  attn_kernel<<<512, 256, 0, stream>>>(qb, kb, vt, ao);
  gemm_kernel<2><<<512, 256, 0, stream>>>(ao, wot, d_out, bo);
}

// Round 6
// 138.897 us; speedup vs baseline: 2.9561x; 1.4138x over previous
//
#include <hip/hip_runtime.h>

#define XD 512
#define HEADS 8
#define DH 64
#define NSEQ 2048
#define NBATCH 4
#define NROWS (NBATCH*NSEQ)   // 8192

#define SCALE_L2E 0.18033688011112042f   // 0.125 * log2(e)
#define DEFER_THR 4.0f

typedef __attribute__((ext_vector_type(8))) short bf16x8;
typedef __attribute__((ext_vector_type(8))) unsigned short u16x8;
typedef __attribute__((ext_vector_type(4))) float f32x4;

__device__ __forceinline__ unsigned short f2bf(float f) {
  union { float f; unsigned u; } v; v.f = f;
  return (unsigned short)((v.u + 0x7fffu + ((v.u >> 16) & 1u)) >> 16);
}

__device__ __forceinline__ float fexp2(float x) {
#if __has_builtin(__builtin_amdgcn_exp2f)
  return __builtin_amdgcn_exp2f(x);
#else
  return exp2f(x);
#endif
}

__device__ __forceinline__ unsigned cvt_pk_bf16(float lo, float hi) {
  unsigned r;
  asm("v_cvt_pk_bf16_f32 %0, %1, %2" : "=v"(r) : "v"(lo), "v"(hi));
  return r;
}

// async global->LDS, 16B per lane; LDS dest must be wave-uniform base (HW adds lane*16)
__device__ __forceinline__ void gload_lds16(const unsigned short* g, unsigned short* l) {
  __builtin_amdgcn_global_load_lds(
      (const __attribute__((address_space(1))) unsigned int*)g,
      (__attribute__((address_space(3))) unsigned int*)l, 16, 0, 0);
}

// ---------------- z path: LN(z) @ Wz -> silu -> z1,z2  (tiny) ----------------
__global__ __launch_bounds__(256) void zpath_kernel(
    const float* __restrict__ z, const float* __restrict__ g, const float* __restrict__ b,
    const float* __restrict__ Wz, float* __restrict__ z12) {
  int bb = blockIdx.x;            // batch
  int t = threadIdx.x;
  float zv[16];
  float mean = 0.f;
#pragma unroll
  for (int i = 0; i < 16; ++i) { zv[i] = z[bb * 16 + i]; mean += zv[i]; }
  mean *= (1.f / 16.f);
  float var = 0.f;
#pragma unroll
  for (int i = 0; i < 16; ++i) { float d = zv[i] - mean; var += d * d; }
  var *= (1.f / 16.f);
  float rs = rsqrtf(var + 1e-5f);
  float zn[16];
#pragma unroll
  for (int i = 0; i < 16; ++i) zn[i] = (zv[i] - mean) * rs * g[i] + b[i];
  for (int c = t; c < 1024; c += 256) {
    float acc = 0.f;
#pragma unroll
    for (int i = 0; i < 16; ++i) acc += zn[i] * Wz[i * 1024 + c];
    float s = acc / (1.f + __expf(-acc));   // silu
    z12[bb * 1024 + c] = s;
  }
}

// ---------------- x_mod = LN(x)*z1 + z2 -> bf16 [8192,512] ----------------
__global__ __launch_bounds__(256) void xmod_kernel(
    const float* __restrict__ x, const float* __restrict__ g, const float* __restrict__ b,
    const float* __restrict__ z12, unsigned short* __restrict__ xm) {
  int wave = threadIdx.x >> 6, lane = threadIdx.x & 63;
  int row = blockIdx.x * 4 + wave;
  const float* xr = x + (size_t)row * XD;
  float4 v0 = ((const float4*)xr)[lane * 2];
  float4 v1 = ((const float4*)xr)[lane * 2 + 1];
  float vv[8] = {v0.x, v0.y, v0.z, v0.w, v1.x, v1.y, v1.z, v1.w};
  float sum = 0.f, sq = 0.f;
#pragma unroll
  for (int i = 0; i < 8; ++i) { sum += vv[i]; sq += vv[i] * vv[i]; }
#pragma unroll
  for (int o = 32; o; o >>= 1) { sum += __shfl_xor(sum, o); sq += __shfl_xor(sq, o); }
  float mean = sum * (1.f / 512.f);
  float var = sq * (1.f / 512.f) - mean * mean;
  float rs = rsqrtf(var + 1e-5f);
  int bb = row >> 11;
  const float* zz = z12 + bb * 1024;
  int c0 = lane * 8;
  u16x8 o8;
#pragma unroll
  for (int i = 0; i < 8; ++i) {
    int c = c0 + i;
    float t = (vv[i] - mean) * rs * g[c] + b[c];
    t = t * zz[c] + zz[512 + c];
    o8[i] = f2bf(t);
  }
  *(u16x8*)(xm + (size_t)row * XD + c0) = o8;
}

// ------- fused weight transpose fp32[K,N] -> bf16 [n][k] for Wq,Wk,Wv,Wo -------
__global__ __launch_bounds__(256) void wtrans4_kernel(
    const float* __restrict__ W0, const float* __restrict__ W1,
    const float* __restrict__ W2, const float* __restrict__ W3,
    unsigned short* __restrict__ dst) {
  int idx = blockIdx.x * 256 + threadIdx.x;   // 0..1048575
  int w = idx >> 18;                           // which weight (block-uniform)
  int e = idx & 262143;                        // n*512 + k
  int n = e >> 9, k = e & 511;
  const float* W = (w == 0) ? W0 : (w == 1) ? W1 : (w == 2) ? W2 : W3;
  dst[idx] = f2bf(W[k * 512 + n]);
}

// ---------- GEMM (m97-style): C[8192,512] = A_bf16 @ W, LDS-staged ----------
// BM=128, BN=64, BK=64; 256 threads = 4 waves (2 m-waves x 2 n-waves);
// per wave 64x32 output = 4x2 frags of 16x16. global_load_lds width-16 staging.
// MODE 0: bf16 row-major out; MODE 1: per-head-transposed+slot-permuted V out;
// MODE 2: fp32 out + bias
template <int MODE>
__global__ __launch_bounds__(256, 2) void gemm_kernel(
    const unsigned short* __restrict__ A, const unsigned short* __restrict__ Wt,
    void* __restrict__ out, const float* __restrict__ bias) {
  __shared__ unsigned short Alds[128 * 64];
  __shared__ unsigned short Blds[64 * 64];
  int widx = threadIdx.x >> 6, lane = threadIdx.x & 63;
  int blk = blockIdx.x;
  int nt = blk & 7, mt = blk >> 3;       // 8 n-tiles, 64 m-tiles
  int blkM = mt * 128, blkN = nt * 64;
  int wr = widx >> 1, wc = widx & 1;
  int lr = lane & 15, lg = lane >> 4;
  int srow = lane >> 3, scol = (lane & 7) * 8;   // staging: 8 rows/instr, 8 cols/lane

  const unsigned short* Ag = A + (size_t)(blkM + widx * 32 + srow) * 512 + scol;
  const unsigned short* Bg = Wt + (size_t)(blkN + widx * 16 + srow) * 512 + scol;
  unsigned short* Al = &Alds[(widx * 32) * 64];   // wave-uniform LDS bases
  unsigned short* Bl = &Blds[(widx * 16) * 64];

  f32x4 acc[4][2] = {};

  for (int kc = 0; kc < 512; kc += 64) {
#pragma unroll
    for (int i = 0; i < 4; ++i)
      gload_lds16(Ag + (size_t)(i * 8) * 512 + kc, Al + (i * 8) * 64);
#pragma unroll
    for (int i = 0; i < 2; ++i)
      gload_lds16(Bg + (size_t)(i * 8) * 512 + kc, Bl + (i * 8) * 64);
    __syncthreads();   // drains global_load_lds + all waves staged

#pragma unroll
    for (int kh = 0; kh < 2; ++kh) {
      bf16x8 bfr[2];
#pragma unroll
      for (int ni = 0; ni < 2; ++ni)
        bfr[ni] = *(const bf16x8*)&Blds[(wc * 32 + ni * 16 + lr) * 64 + kh * 32 + lg * 8];
#pragma unroll
      for (int mi = 0; mi < 4; ++mi) {
        bf16x8 afr = *(const bf16x8*)&Alds[(wr * 64 + mi * 16 + lr) * 64 + kh * 32 + lg * 8];
#pragma unroll
        for (int ni = 0; ni < 2; ++ni)
          acc[mi][ni] = __builtin_amdgcn_mfma_f32_16x16x32_bf16(afr, bfr[ni], acc[mi][ni], 0, 0, 0);
      }
    }
    __syncthreads();   // protect LDS before next stage
  }

#pragma unroll
  for (int mi = 0; mi < 4; ++mi)
#pragma unroll
    for (int ni = 0; ni < 2; ++ni) {
      int col = blkN + wc * 32 + ni * 16 + lr;
#pragma unroll
      for (int j = 0; j < 4; ++j) {
        int row = blkM + wr * 64 + mi * 16 + lg * 4 + j;
        float v = acc[mi][ni][j];
        if (MODE == 0) {
          ((unsigned short*)out)[(size_t)row * 512 + col] = f2bf(v);
        } else if (MODE == 1) {
          int bb = row >> 11, n = row & 2047, h = col >> 6, d = col & 63;
          // key-slot permutation within each 32-key block so attn's post-softmax
          // P (packed straight from QK^T C-layout) is a valid 16x16x32 B-fragment
          int j5 = n & 31;
          int slot = ((j5 >> 2) & 3) * 8 + ((j5 >> 4) & 1) * 4 + (j5 & 3);
          int np = (n & ~31) | slot;
          ((unsigned short*)out)[(((size_t)(bb * HEADS + h) * DH + d) << 11) + np] = f2bf(v);
        } else {
          ((float*)out)[(size_t)row * 512 + col] = v + bias[col];
        }
      }
    }
}

// ---------------- flash attention, swapped-QK / permuted-V ----------------
// Block = 4 waves sharing one (b,h); K/V tiles (64 keys) staged in LDS,
// double-buffered, global_load_lds + XOR-swizzled source (rule #21: linear
// LDS dest + inverse-swizzled global src + swizzled ds_read). Softmax math
// is verbatim the R3-passing version.

#define KVCHUNK 64
#define NCHUNK (NSEQ / KVCHUNK)   // 32

// stage one 64x64-short tile pair into Klds[buf]/Vlds[buf]; per wave 2x1KB each
#define STAGE(buf, kcc) do {                                              \
    _Pragma("unroll")                                                     \
    for (int i = 0; i < 2; ++i) {                                         \
      int rb = widx * 16 + i * 8;                                         \
      int row = rb + (lane >> 3);                                         \
      int csrc = (lane & 7) ^ (row & 7);                                  \
      gload_lds16(Kg + (size_t)((kcc) + row) * 512 + csrc * 8, &Klds[buf][rb * 64]); \
      gload_lds16(Vg + (size_t)row * NSEQ + (kcc) + csrc * 8, &Vlds[buf][rb * 64]); \
    }                                                                     \
  } while (0)

// process 32 keys (sub=0/1) from the staged tile
#define PROCESS_LDS(kb_, vb_, sub) do {                                   \
    bf16x8 kf[2][2], vf[4];                                               \
    _Pragma("unroll")                                                     \
    for (int kt = 0; kt < 2; ++kt) {                                      \
      int row = (sub) * 32 + kt * 16 + lr;                                \
      _Pragma("unroll")                                                   \
      for (int hf = 0; hf < 2; ++hf)                                      \
        kf[kt][hf] = *(const bf16x8*)((kb_) + row * 64 + (((hf * 4 + lg) ^ (row & 7)) * 8)); \
    }                                                                     \
    _Pragma("unroll")                                                     \
    for (int dt = 0; dt < 4; ++dt) {                                      \
      int row = dt * 16 + lr;                                             \
      vf[dt] = *(const bf16x8*)((vb_) + row * 64 + ((((sub) * 4 + lg) ^ (row & 7)) * 8)); \
    }                                                                     \
    f32x4 s[2][2] = {};                                                   \
    _Pragma("unroll")                                                     \
    for (int qt = 0; qt < 2; ++qt)                                        \
      _Pragma("unroll")                                                   \
      for (int kt = 0; kt < 2; ++kt) {                                    \
        s[qt][kt] = __builtin_amdgcn_mfma_f32_16x16x32_bf16(kf[kt][0], qf[qt][0], s[qt][kt], 0, 0, 0); \
        s[qt][kt] = __builtin_amdgcn_mfma_f32_16x16x32_bf16(kf[kt][1], qf[qt][1], s[qt][kt], 0, 0, 0); \
      }                                                                   \
    float t[2][8], mx[2];                                                 \
    _Pragma("unroll")                                                     \
    for (int qt = 0; qt < 2; ++qt) {                                      \
      _Pragma("unroll")                                                   \
      for (int kt = 0; kt < 2; ++kt)                                      \
        _Pragma("unroll")                                                 \
        for (int j = 0; j < 4; ++j) t[qt][kt * 4 + j] = s[qt][kt][j] * SCALE_L2E; \
      float m8 = t[qt][0];                                                \
      _Pragma("unroll")                                                   \
      for (int i = 1; i < 8; ++i) m8 = fmaxf(m8, t[qt][i]);               \
      m8 = fmaxf(m8, __shfl_xor(m8, 16));                                 \
      m8 = fmaxf(m8, __shfl_xor(m8, 32));                                 \
      mx[qt] = m8;                                                        \
    }                                                                     \
    bool grow = (mx[0] > m[0] + DEFER_THR) || (mx[1] > m[1] + DEFER_THR); \
    if (__any((int)grow)) {                                               \
      _Pragma("unroll")                                                   \
      for (int qt = 0; qt < 2; ++qt) {                                    \
        float mn = fmaxf(m[qt], mx[qt]);                                  \
        float al = fexp2(m[qt] - mn);                                     \
        m[qt] = mn;                                                       \
        l[qt] *= al;                                                      \
        _Pragma("unroll")                                                 \
        for (int dt = 0; dt < 4; ++dt)                                    \
          _Pragma("unroll")                                               \
          for (int j = 0; j < 4; ++j) o[qt][dt][j] *= al;                 \
      }                                                                   \
    }                                                                     \
    _Pragma("unroll")                                                     \
    for (int qt = 0; qt < 2; ++qt) {                                      \
      float p[8]; float rs = 0.f;                                         \
      _Pragma("unroll")                                                   \
      for (int i = 0; i < 8; ++i) { p[i] = fexp2(t[qt][i] - m[qt]); rs += p[i]; } \
      rs += __shfl_xor(rs, 16);                                           \
      rs += __shfl_xor(rs, 32);                                           \
      l[qt] += rs;                                                        \
      union { unsigned w[4]; bf16x8 v; } pf;                              \
      _Pragma("unroll")                                                   \
      for (int d2 = 0; d2 < 4; ++d2) pf.w[d2] = cvt_pk_bf16(p[d2 * 2], p[d2 * 2 + 1]); \
      _Pragma("unroll")                                                   \
      for (int dt = 0; dt < 4; ++dt)                                      \
        o[qt][dt] = __builtin_amdgcn_mfma_f32_16x16x32_bf16(vf[dt], pf.v, o[qt][dt], 0, 0, 0); \
    }                                                                     \
  } while (0)

__global__ __launch_bounds__(256, 2) void attn_kernel(
    const unsigned short* __restrict__ Q, const unsigned short* __restrict__ K,
    const unsigned short* __restrict__ VT, unsigned short* __restrict__ O) {
  __shared__ unsigned short Klds[2][64 * 64];
  __shared__ unsigned short Vlds[2][64 * 64];
  int widx = threadIdx.x >> 6, lane = threadIdx.x & 63;
  int blk = blockIdx.x;
  int xcd = blk & 7;
  int idx = blk >> 3;                 // 0..63 within XCD
  int bh = xcd * 4 + (idx >> 4);      // 0..31 (all 4 waves share bh)
  int qb = (idx & 15) * 4 + widx;     // 0..63
  int b = bh >> 3, h = bh & 7;
  int lr = lane & 15, lg = lane >> 4;

  const size_t qk_base = (size_t)b * NSEQ * 512 + h * 64 + lg * 8;
  bf16x8 qf[2][2];
#pragma unroll
  for (int qt = 0; qt < 2; ++qt) {
    size_t qa = qk_base + (size_t)(qb * 32 + qt * 16 + lr) * 512;
    qf[qt][0] = *(const bf16x8*)(Q + qa);
    qf[qt][1] = *(const bf16x8*)(Q + qa + 32);
  }
  const unsigned short* Kg = K + (size_t)b * NSEQ * 512 + h * 64;
  const unsigned short* Vg = VT + (size_t)bh * DH * NSEQ;

  float m[2] = {-3.0e38f, -3.0e38f};
  float l[2] = {0.f, 0.f};
  f32x4 o[2][4] = {};

  STAGE(0, 0);
  __syncthreads();
  int cur = 0;
  for (int t = 0; t < NCHUNK; ++t) {
    if (t + 1 < NCHUNK) STAGE(cur ^ 1, (t + 1) * KVCHUNK);
    const unsigned short* kb_ = &Klds[cur][0];
    const unsigned short* vb_ = &Vlds[cur][0];
    PROCESS_LDS(kb_, vb_, 0);
    PROCESS_LDS(kb_, vb_, 1);
    __syncthreads();   // drains next-tile staging; guards LDS reuse
    cur ^= 1;
  }

#pragma unroll
  for (int qt = 0; qt < 2; ++qt) {
    float inv = 1.f / l[qt];
    size_t row = (size_t)(b * NSEQ + qb * 32 + qt * 16 + lr) * 512 + h * 64 + lg * 4;
#pragma unroll
    for (int dt = 0; dt < 4; ++dt) {
      unsigned w0 = cvt_pk_bf16(o[qt][dt][0] * inv, o[qt][dt][1] * inv);
      unsigned w1 = cvt_pk_bf16(o[qt][dt][2] * inv, o[qt][dt][3] * inv);
      uint2 st = {w0, w1};
      *(uint2*)(O + row + dt * 16) = st;
    }
  }
}

extern "C" void kernel_launch(void* const* d_in, const int* in_sizes, int n_in,
                              void* d_out, int out_size, void* d_ws, size_t ws_size,
                              hipStream_t stream) {
  const float* x   = (const float*)d_in[0];
  const float* z   = (const float*)d_in[1];
  const float* lxg = (const float*)d_in[2];
  const float* lxb = (const float*)d_in[3];
  const float* lzg = (const float*)d_in[4];
  const float* lzb = (const float*)d_in[5];
  const float* Wq  = (const float*)d_in[6];
  const float* Wk  = (const float*)d_in[7];
  const float* Wv  = (const float*)d_in[8];
  const float* Wz  = (const float*)d_in[9];
  const float* Wo  = (const float*)d_in[10];
  const float* bo  = (const float*)d_in[11];

  char* ws = (char*)d_ws;
  unsigned short* xm  = (unsigned short*)(ws);
  unsigned short* qb  = (unsigned short*)(ws + 8388608);
  unsigned short* kb  = (unsigned short*)(ws + 16777216);
  unsigned short* vt  = (unsigned short*)(ws + 25165824);
  unsigned short* ao  = (unsigned short*)(ws + 33554432);
  unsigned short* wqt = (unsigned short*)(ws + 41943040);   // wq,wk,wv,wo contiguous
  unsigned short* wkt = (unsigned short*)(ws + 42467328);
  unsigned short* wvt = (unsigned short*)(ws + 42991616);
  unsigned short* wot = (unsigned short*)(ws + 43515904);
  float*          z12 = (float*)(ws + 44040192);

  zpath_kernel<<<NBATCH, 256, 0, stream>>>(z, lzg, lzb, Wz, z12);
  xmod_kernel<<<NROWS / 4, 256, 0, stream>>>(x, lxg, lxb, z12, xm);
  wtrans4_kernel<<<4096, 256, 0, stream>>>(Wq, Wk, Wv, Wo, wqt);
  gemm_kernel<0><<<512, 256, 0, stream>>>(xm, wqt, qb, nullptr);
  gemm_kernel<0><<<512, 256, 0, stream>>>(xm, wkt, kb, nullptr);
  gemm_kernel<1><<<512, 256, 0, stream>>>(xm, wvt, vt, nullptr);
  attn_kernel<<<512, 256, 0, stream>>>(qb, kb, vt, ao);
  gemm_kernel<2><<<512, 256, 0, stream>>>(ao, wot, d_out, bo);
}

// Round 7
// 136.620 us; speedup vs baseline: 3.0053x; 1.0167x over previous
//
#include <hip/hip_runtime.h>

#define XD 512
#define HEADS 8
#define DH 64
#define NSEQ 2048
#define NBATCH 4
#define NROWS (NBATCH*NSEQ)   // 8192

#define SCALE_L2E 0.18033688011112042f   // 0.125 * log2(e)
#define DEFER_THR 4.0f

typedef __attribute__((ext_vector_type(8))) short bf16x8;
typedef __attribute__((ext_vector_type(8))) unsigned short u16x8;
typedef __attribute__((ext_vector_type(4))) float f32x4;

__device__ __forceinline__ unsigned short f2bf(float f) {
  union { float f; unsigned u; } v; v.f = f;
  return (unsigned short)((v.u + 0x7fffu + ((v.u >> 16) & 1u)) >> 16);
}

__device__ __forceinline__ float fexp2(float x) {
#if __has_builtin(__builtin_amdgcn_exp2f)
  return __builtin_amdgcn_exp2f(x);
#else
  return exp2f(x);
#endif
}

__device__ __forceinline__ unsigned cvt_pk_bf16(float lo, float hi) {
  unsigned r;
  asm("v_cvt_pk_bf16_f32 %0, %1, %2" : "=v"(r) : "v"(lo), "v"(hi));
  return r;
}

// async global->LDS, 16B per lane; LDS dest must be wave-uniform base (HW adds lane*16)
__device__ __forceinline__ void gload_lds16(const unsigned short* g, unsigned short* l) {
  __builtin_amdgcn_global_load_lds(
      (const __attribute__((address_space(1))) unsigned int*)g,
      (__attribute__((address_space(3))) unsigned int*)l, 16, 0, 0);
}

// ---------------- z path: LN(z) @ Wz -> silu -> z1,z2  (tiny) ----------------
__global__ __launch_bounds__(256) void zpath_kernel(
    const float* __restrict__ z, const float* __restrict__ g, const float* __restrict__ b,
    const float* __restrict__ Wz, float* __restrict__ z12) {
  int bb = blockIdx.x;            // batch
  int t = threadIdx.x;
  float zv[16];
  float mean = 0.f;
#pragma unroll
  for (int i = 0; i < 16; ++i) { zv[i] = z[bb * 16 + i]; mean += zv[i]; }
  mean *= (1.f / 16.f);
  float var = 0.f;
#pragma unroll
  for (int i = 0; i < 16; ++i) { float d = zv[i] - mean; var += d * d; }
  var *= (1.f / 16.f);
  float rs = rsqrtf(var + 1e-5f);
  float zn[16];
#pragma unroll
  for (int i = 0; i < 16; ++i) zn[i] = (zv[i] - mean) * rs * g[i] + b[i];
  for (int c = t; c < 1024; c += 256) {
    float acc = 0.f;
#pragma unroll
    for (int i = 0; i < 16; ++i) acc += zn[i] * Wz[i * 1024 + c];
    float s = acc / (1.f + __expf(-acc));   // silu
    z12[bb * 1024 + c] = s;
  }
}

// ---------------- x_mod = LN(x)*z1 + z2 -> bf16 [8192,512] ----------------
__global__ __launch_bounds__(256) void xmod_kernel(
    const float* __restrict__ x, const float* __restrict__ g, const float* __restrict__ b,
    const float* __restrict__ z12, unsigned short* __restrict__ xm) {
  int wave = threadIdx.x >> 6, lane = threadIdx.x & 63;
  int row = blockIdx.x * 4 + wave;
  const float* xr = x + (size_t)row * XD;
  float4 v0 = ((const float4*)xr)[lane * 2];
  float4 v1 = ((const float4*)xr)[lane * 2 + 1];
  float vv[8] = {v0.x, v0.y, v0.z, v0.w, v1.x, v1.y, v1.z, v1.w};
  float sum = 0.f, sq = 0.f;
#pragma unroll
  for (int i = 0; i < 8; ++i) { sum += vv[i]; sq += vv[i] * vv[i]; }
#pragma unroll
  for (int o = 32; o; o >>= 1) { sum += __shfl_xor(sum, o); sq += __shfl_xor(sq, o); }
  float mean = sum * (1.f / 512.f);
  float var = sq * (1.f / 512.f) - mean * mean;
  float rs = rsqrtf(var + 1e-5f);
  int bb = row >> 11;
  const float* zz = z12 + bb * 1024;
  int c0 = lane * 8;
  u16x8 o8;
#pragma unroll
  for (int i = 0; i < 8; ++i) {
    int c = c0 + i;
    float t = (vv[i] - mean) * rs * g[c] + b[c];
    t = t * zz[c] + zz[512 + c];
    o8[i] = f2bf(t);
  }
  *(u16x8*)(xm + (size_t)row * XD + c0) = o8;
}

// ------- fused weight transpose fp32[K,N] -> bf16 [n][k] for Wq,Wk,Wv,Wo -------
__global__ __launch_bounds__(256) void wtrans4_kernel(
    const float* __restrict__ W0, const float* __restrict__ W1,
    const float* __restrict__ W2, const float* __restrict__ W3,
    unsigned short* __restrict__ dst) {
  int idx = blockIdx.x * 256 + threadIdx.x;   // 0..1048575
  int w = idx >> 18;                           // which weight (block-uniform)
  int e = idx & 262143;                        // n*512 + k
  int n = e >> 9, k = e & 511;
  const float* W = (w == 0) ? W0 : (w == 1) ? W1 : (w == 2) ? W2 : W3;
  dst[idx] = f2bf(W[k * 512 + n]);
}

// ---------- GEMM (m97-style): C[8192,512] = A_bf16 @ W, LDS-staged ----------
// BM=128, BN=64, BK=64; 256 threads = 4 waves (2 m-waves x 2 n-waves);
// per wave 64x32 output = 4x2 frags of 16x16. global_load_lds width-16 staging.
// MODE 0: bf16 row-major out; MODE 1: per-head-transposed+slot-permuted V out;
// MODE 2: fp32 out + bias
template <int MODE>
__global__ __launch_bounds__(256, 2) void gemm_kernel(
    const unsigned short* __restrict__ A, const unsigned short* __restrict__ Wt,
    void* __restrict__ out, const float* __restrict__ bias) {
  __shared__ unsigned short Alds[128 * 64];
  __shared__ unsigned short Blds[64 * 64];
  int widx = threadIdx.x >> 6, lane = threadIdx.x & 63;
  int blk = blockIdx.x;
  int nt = blk & 7, mt = blk >> 3;       // 8 n-tiles, 64 m-tiles
  int blkM = mt * 128, blkN = nt * 64;
  int wr = widx >> 1, wc = widx & 1;
  int lr = lane & 15, lg = lane >> 4;
  int srow = lane >> 3, scol = (lane & 7) * 8;   // staging: 8 rows/instr, 8 cols/lane

  const unsigned short* Ag = A + (size_t)(blkM + widx * 32 + srow) * 512 + scol;
  const unsigned short* Bg = Wt + (size_t)(blkN + widx * 16 + srow) * 512 + scol;
  unsigned short* Al = &Alds[(widx * 32) * 64];   // wave-uniform LDS bases
  unsigned short* Bl = &Blds[(widx * 16) * 64];

  f32x4 acc[4][2] = {};

  for (int kc = 0; kc < 512; kc += 64) {
#pragma unroll
    for (int i = 0; i < 4; ++i)
      gload_lds16(Ag + (size_t)(i * 8) * 512 + kc, Al + (i * 8) * 64);
#pragma unroll
    for (int i = 0; i < 2; ++i)
      gload_lds16(Bg + (size_t)(i * 8) * 512 + kc, Bl + (i * 8) * 64);
    __syncthreads();   // drains global_load_lds + all waves staged

#pragma unroll
    for (int kh = 0; kh < 2; ++kh) {
      bf16x8 bfr[2];
#pragma unroll
      for (int ni = 0; ni < 2; ++ni)
        bfr[ni] = *(const bf16x8*)&Blds[(wc * 32 + ni * 16 + lr) * 64 + kh * 32 + lg * 8];
#pragma unroll
      for (int mi = 0; mi < 4; ++mi) {
        bf16x8 afr = *(const bf16x8*)&Alds[(wr * 64 + mi * 16 + lr) * 64 + kh * 32 + lg * 8];
#pragma unroll
        for (int ni = 0; ni < 2; ++ni)
          acc[mi][ni] = __builtin_amdgcn_mfma_f32_16x16x32_bf16(afr, bfr[ni], acc[mi][ni], 0, 0, 0);
      }
    }
    __syncthreads();   // protect LDS before next stage
  }

#pragma unroll
  for (int mi = 0; mi < 4; ++mi)
#pragma unroll
    for (int ni = 0; ni < 2; ++ni) {
      int col = blkN + wc * 32 + ni * 16 + lr;
#pragma unroll
      for (int j = 0; j < 4; ++j) {
        int row = blkM + wr * 64 + mi * 16 + lg * 4 + j;
        float v = acc[mi][ni][j];
        if (MODE == 0) {
          ((unsigned short*)out)[(size_t)row * 512 + col] = f2bf(v);
        } else if (MODE == 1) {
          int bb = row >> 11, n = row & 2047, h = col >> 6, d = col & 63;
          // key-slot permutation within each 32-key block so attn's post-softmax
          // P (packed straight from QK^T C-layout) is a valid 16x16x32 B-fragment
          int j5 = n & 31;
          int slot = ((j5 >> 2) & 3) * 8 + ((j5 >> 4) & 1) * 4 + (j5 & 3);
          int np = (n & ~31) | slot;
          ((unsigned short*)out)[(((size_t)(bb * HEADS + h) * DH + d) << 11) + np] = f2bf(v);
        } else {
          ((float*)out)[(size_t)row * 512 + col] = v + bias[col];
        }
      }
    }
}

// ---------------- flash attention, swapped-QK / permuted-V ----------------
// Block = 4 waves sharing one (b,h), each wave owns 16 q-rows (QBLK=16).
// 1024 blocks -> 4 blocks/CU -> 4 waves/SIMD for latency hiding.
// K/V tiles (64 keys) staged in LDS, double-buffered, global_load_lds with
// XOR-swizzled source (rule #21). Softmax math verbatim R5-passing, single-qt.

#define KVCHUNK 64
#define NCHUNK (NSEQ / KVCHUNK)   // 32

// stage one 64x64-short tile pair into Klds[buf]/Vlds[buf]; per wave 2x1KB each
#define STAGE(buf, kcc) do {                                              \
    _Pragma("unroll")                                                     \
    for (int i = 0; i < 2; ++i) {                                         \
      int rb = widx * 16 + i * 8;                                         \
      int row = rb + (lane >> 3);                                         \
      int csrc = (lane & 7) ^ (row & 7);                                  \
      gload_lds16(Kg + (size_t)((kcc) + row) * 512 + csrc * 8, &Klds[buf][rb * 64]); \
      gload_lds16(Vg + (size_t)row * NSEQ + (kcc) + csrc * 8, &Vlds[buf][rb * 64]); \
    }                                                                     \
  } while (0)

// process 32 keys (sub=0/1) from the staged tile (single 16-row q-tile)
#define PROCESS_LDS(kb_, vb_, sub) do {                                   \
    bf16x8 kf[2][2], vf[4];                                               \
    _Pragma("unroll")                                                     \
    for (int kt = 0; kt < 2; ++kt) {                                      \
      int row = (sub) * 32 + kt * 16 + lr;                                \
      _Pragma("unroll")                                                   \
      for (int hf = 0; hf < 2; ++hf)                                      \
        kf[kt][hf] = *(const bf16x8*)((kb_) + row * 64 + (((hf * 4 + lg) ^ (row & 7)) * 8)); \
    }                                                                     \
    _Pragma("unroll")                                                     \
    for (int dt = 0; dt < 4; ++dt) {                                      \
      int row = dt * 16 + lr;                                             \
      vf[dt] = *(const bf16x8*)((vb_) + row * 64 + ((((sub) * 4 + lg) ^ (row & 7)) * 8)); \
    }                                                                     \
    f32x4 s[2] = {};                                                      \
    _Pragma("unroll")                                                     \
    for (int kt = 0; kt < 2; ++kt) {                                      \
      s[kt] = __builtin_amdgcn_mfma_f32_16x16x32_bf16(kf[kt][0], qf[0], s[kt], 0, 0, 0); \
      s[kt] = __builtin_amdgcn_mfma_f32_16x16x32_bf16(kf[kt][1], qf[1], s[kt], 0, 0, 0); \
    }                                                                     \
    float tt[8];                                                          \
    _Pragma("unroll")                                                     \
    for (int kt = 0; kt < 2; ++kt)                                        \
      _Pragma("unroll")                                                   \
      for (int j = 0; j < 4; ++j) tt[kt * 4 + j] = s[kt][j] * SCALE_L2E;  \
    float m8 = tt[0];                                                     \
    _Pragma("unroll")                                                     \
    for (int i = 1; i < 8; ++i) m8 = fmaxf(m8, tt[i]);                    \
    m8 = fmaxf(m8, __shfl_xor(m8, 16));                                   \
    m8 = fmaxf(m8, __shfl_xor(m8, 32));                                   \
    bool grow = (m8 > m0 + DEFER_THR);                                    \
    if (__any((int)grow)) {                                               \
      float mn = fmaxf(m0, m8);                                           \
      float al = fexp2(m0 - mn);                                          \
      m0 = mn;                                                            \
      l0 *= al;                                                           \
      _Pragma("unroll")                                                   \
      for (int dt = 0; dt < 4; ++dt)                                      \
        _Pragma("unroll")                                                 \
        for (int j = 0; j < 4; ++j) o[dt][j] *= al;                       \
    }                                                                     \
    float p[8]; float rs = 0.f;                                           \
    _Pragma("unroll")                                                     \
    for (int i = 0; i < 8; ++i) { p[i] = fexp2(tt[i] - m0); rs += p[i]; } \
    rs += __shfl_xor(rs, 16);                                             \
    rs += __shfl_xor(rs, 32);                                             \
    l0 += rs;                                                             \
    union { unsigned w[4]; bf16x8 v; } pf;                                \
    _Pragma("unroll")                                                     \
    for (int d2 = 0; d2 < 4; ++d2) pf.w[d2] = cvt_pk_bf16(p[d2 * 2], p[d2 * 2 + 1]); \
    _Pragma("unroll")                                                     \
    for (int dt = 0; dt < 4; ++dt)                                        \
      o[dt] = __builtin_amdgcn_mfma_f32_16x16x32_bf16(vf[dt], pf.v, o[dt], 0, 0, 0); \
  } while (0)

__global__ __launch_bounds__(256, 4) void attn_kernel(
    const unsigned short* __restrict__ Q, const unsigned short* __restrict__ K,
    const unsigned short* __restrict__ VT, unsigned short* __restrict__ O) {
  __shared__ unsigned short Klds[2][64 * 64];
  __shared__ unsigned short Vlds[2][64 * 64];
  int widx = threadIdx.x >> 6, lane = threadIdx.x & 63;
  int blk = blockIdx.x;                // 0..1023
  int xcd = blk & 7;
  int idx = blk >> 3;                  // 0..127 within XCD
  int bh = xcd * 4 + (idx >> 5);       // 0..31 (4 bh per XCD; all 4 waves share bh)
  int qg = idx & 31;                   // 64-row q-group within bh
  int b = bh >> 3, h = bh & 7;
  int lr = lane & 15, lg = lane >> 4;
  int qrow0 = qg * 64 + widx * 16;     // this wave's 16 q-rows

  const size_t qk_base = (size_t)b * NSEQ * 512 + h * 64 + lg * 8;
  bf16x8 qf[2];
  {
    size_t qa = qk_base + (size_t)(qrow0 + lr) * 512;
    qf[0] = *(const bf16x8*)(Q + qa);
    qf[1] = *(const bf16x8*)(Q + qa + 32);
  }
  const unsigned short* Kg = K + (size_t)b * NSEQ * 512 + h * 64;
  const unsigned short* Vg = VT + (size_t)bh * DH * NSEQ;

  float m0 = -3.0e38f;
  float l0 = 0.f;
  f32x4 o[4] = {};

  STAGE(0, 0);
  __syncthreads();
  int cur = 0;
  for (int t = 0; t < NCHUNK; ++t) {
    if (t + 1 < NCHUNK) STAGE(cur ^ 1, (t + 1) * KVCHUNK);
    const unsigned short* kb_ = &Klds[cur][0];
    const unsigned short* vb_ = &Vlds[cur][0];
    PROCESS_LDS(kb_, vb_, 0);
    PROCESS_LDS(kb_, vb_, 1);
    __syncthreads();   // drains next-tile staging; guards LDS reuse
    cur ^= 1;
  }

  {
    float inv = 1.f / l0;
    size_t row = (size_t)(b * NSEQ + qrow0 + lr) * 512 + h * 64 + lg * 4;
#pragma unroll
    for (int dt = 0; dt < 4; ++dt) {
      unsigned w0 = cvt_pk_bf16(o[dt][0] * inv, o[dt][1] * inv);
      unsigned w1 = cvt_pk_bf16(o[dt][2] * inv, o[dt][3] * inv);
      uint2 st = {w0, w1};
      *(uint2*)(O + row + dt * 16) = st;
    }
  }
}

extern "C" void kernel_launch(void* const* d_in, const int* in_sizes, int n_in,
                              void* d_out, int out_size, void* d_ws, size_t ws_size,
                              hipStream_t stream) {
  const float* x   = (const float*)d_in[0];
  const float* z   = (const float*)d_in[1];
  const float* lxg = (const float*)d_in[2];
  const float* lxb = (const float*)d_in[3];
  const float* lzg = (const float*)d_in[4];
  const float* lzb = (const float*)d_in[5];
  const float* Wq  = (const float*)d_in[6];
  const float* Wk  = (const float*)d_in[7];
  const float* Wv  = (const float*)d_in[8];
  const float* Wz  = (const float*)d_in[9];
  const float* Wo  = (const float*)d_in[10];
  const float* bo  = (const float*)d_in[11];

  char* ws = (char*)d_ws;
  unsigned short* xm  = (unsigned short*)(ws);
  unsigned short* qb  = (unsigned short*)(ws + 8388608);
  unsigned short* kb  = (unsigned short*)(ws + 16777216);
  unsigned short* vt  = (unsigned short*)(ws + 25165824);
  unsigned short* ao  = (unsigned short*)(ws + 33554432);
  unsigned short* wqt = (unsigned short*)(ws + 41943040);   // wq,wk,wv,wo contiguous
  unsigned short* wkt = (unsigned short*)(ws + 42467328);
  unsigned short* wvt = (unsigned short*)(ws + 42991616);
  unsigned short* wot = (unsigned short*)(ws + 43515904);
  float*          z12 = (float*)(ws + 44040192);

  zpath_kernel<<<NBATCH, 256, 0, stream>>>(z, lzg, lzb, Wz, z12);
  xmod_kernel<<<NROWS / 4, 256, 0, stream>>>(x, lxg, lxb, z12, xm);
  wtrans4_kernel<<<4096, 256, 0, stream>>>(Wq, Wk, Wv, Wo, wqt);
  gemm_kernel<0><<<512, 256, 0, stream>>>(xm, wqt, qb, nullptr);
  gemm_kernel<0><<<512, 256, 0, stream>>>(xm, wkt, kb, nullptr);
  gemm_kernel<1><<<512, 256, 0, stream>>>(xm, wvt, vt, nullptr);
  attn_kernel<<<1024, 256, 0, stream>>>(qb, kb, vt, ao);
  gemm_kernel<2><<<512, 256, 0, stream>>>(ao, wot, d_out, bo);
}

// Round 8
// 121.188 us; speedup vs baseline: 3.3880x; 1.1273x over previous
//
#include <hip/hip_runtime.h>

#define XD 512
#define HEADS 8
#define DH 64
#define NSEQ 2048
#define NBATCH 4
#define NROWS (NBATCH*NSEQ)   // 8192

#define SCALE_L2E 0.18033688011112042f   // 0.125 * log2(e)
#define DEFER_THR 4.0f

typedef __attribute__((ext_vector_type(8))) short bf16x8;
typedef __attribute__((ext_vector_type(8))) unsigned short u16x8;
typedef __attribute__((ext_vector_type(4))) float f32x4;

__device__ __forceinline__ unsigned short f2bf(float f) {
  union { float f; unsigned u; } v; v.f = f;
  return (unsigned short)((v.u + 0x7fffu + ((v.u >> 16) & 1u)) >> 16);
}

__device__ __forceinline__ float fexp2(float x) {
#if __has_builtin(__builtin_amdgcn_exp2f)
  return __builtin_amdgcn_exp2f(x);
#else
  return exp2f(x);
#endif
}

__device__ __forceinline__ unsigned cvt_pk_bf16(float lo, float hi) {
  unsigned r;
  asm("v_cvt_pk_bf16_f32 %0, %1, %2" : "=v"(r) : "v"(lo), "v"(hi));
  return r;
}

// async global->LDS, 16B per lane; LDS dest must be wave-uniform base (HW adds lane*16)
__device__ __forceinline__ void gload_lds16(const unsigned short* g, unsigned short* l) {
  __builtin_amdgcn_global_load_lds(
      (const __attribute__((address_space(1))) unsigned int*)g,
      (__attribute__((address_space(3))) unsigned int*)l, 16, 0, 0);
}

// ---------------- z path: LN(z) @ Wz -> silu -> z1,z2  (tiny) ----------------
__global__ __launch_bounds__(256) void zpath_kernel(
    const float* __restrict__ z, const float* __restrict__ g, const float* __restrict__ b,
    const float* __restrict__ Wz, float* __restrict__ z12) {
  int bb = blockIdx.x;            // batch
  int t = threadIdx.x;
  float zv[16];
  float mean = 0.f;
#pragma unroll
  for (int i = 0; i < 16; ++i) { zv[i] = z[bb * 16 + i]; mean += zv[i]; }
  mean *= (1.f / 16.f);
  float var = 0.f;
#pragma unroll
  for (int i = 0; i < 16; ++i) { float d = zv[i] - mean; var += d * d; }
  var *= (1.f / 16.f);
  float rs = rsqrtf(var + 1e-5f);
  float zn[16];
#pragma unroll
  for (int i = 0; i < 16; ++i) zn[i] = (zv[i] - mean) * rs * g[i] + b[i];
  for (int c = t; c < 1024; c += 256) {
    float acc = 0.f;
#pragma unroll
    for (int i = 0; i < 16; ++i) acc += zn[i] * Wz[i * 1024 + c];
    float s = acc / (1.f + __expf(-acc));   // silu
    z12[bb * 1024 + c] = s;
  }
}

// ---------------- x_mod = LN(x)*z1 + z2 -> bf16 [8192,512] ----------------
__global__ __launch_bounds__(256) void xmod_kernel(
    const float* __restrict__ x, const float* __restrict__ g, const float* __restrict__ b,
    const float* __restrict__ z12, unsigned short* __restrict__ xm) {
  int wave = threadIdx.x >> 6, lane = threadIdx.x & 63;
  int row = blockIdx.x * 4 + wave;
  const float* xr = x + (size_t)row * XD;
  float4 v0 = ((const float4*)xr)[lane * 2];
  float4 v1 = ((const float4*)xr)[lane * 2 + 1];
  float vv[8] = {v0.x, v0.y, v0.z, v0.w, v1.x, v1.y, v1.z, v1.w};
  float sum = 0.f, sq = 0.f;
#pragma unroll
  for (int i = 0; i < 8; ++i) { sum += vv[i]; sq += vv[i] * vv[i]; }
#pragma unroll
  for (int o = 32; o; o >>= 1) { sum += __shfl_xor(sum, o); sq += __shfl_xor(sq, o); }
  float mean = sum * (1.f / 512.f);
  float var = sq * (1.f / 512.f) - mean * mean;
  float rs = rsqrtf(var + 1e-5f);
  int bb = row >> 11;
  const float* zz = z12 + bb * 1024;
  int c0 = lane * 8;
  u16x8 o8;
#pragma unroll
  for (int i = 0; i < 8; ++i) {
    int c = c0 + i;
    float t = (vv[i] - mean) * rs * g[c] + b[c];
    t = t * zz[c] + zz[512 + c];
    o8[i] = f2bf(t);
  }
  *(u16x8*)(xm + (size_t)row * XD + c0) = o8;
}

// ------- fused weight transpose fp32[K,N] -> bf16 [n][k] for Wq,Wk,Wv,Wo -------
__global__ __launch_bounds__(256) void wtrans4_kernel(
    const float* __restrict__ W0, const float* __restrict__ W1,
    const float* __restrict__ W2, const float* __restrict__ W3,
    unsigned short* __restrict__ dst) {
  int idx = blockIdx.x * 256 + threadIdx.x;   // 0..1048575
  int w = idx >> 18;                           // which weight (block-uniform)
  int e = idx & 262143;                        // n*512 + k
  int n = e >> 9, k = e & 511;
  const float* W = (w == 0) ? W0 : (w == 1) ? W1 : (w == 2) ? W2 : W3;
  dst[idx] = f2bf(W[k * 512 + n]);
}

// ---------- fused QKV GEMM: [8192,512] @ [512,1536] (Wt contiguous [n][k]) ----------
// BM=128, BN=64, BK=64; grid 64 mt x 24 nt. Per-block-uniform epilogue by col>>9:
// 0 -> Q bf16 row-major, 1 -> K bf16 row-major, 2 -> V per-head-transposed+slot-permuted.
__global__ __launch_bounds__(256, 2) void gemm_qkv_kernel(
    const unsigned short* __restrict__ A, const unsigned short* __restrict__ Wt,
    unsigned short* __restrict__ Qo, unsigned short* __restrict__ Ko,
    unsigned short* __restrict__ Vo) {
  __shared__ unsigned short Alds[128 * 64];
  __shared__ unsigned short Blds[64 * 64];
  int widx = threadIdx.x >> 6, lane = threadIdx.x & 63;
  int blk = blockIdx.x;
  int nt = blk % 24, mt = blk / 24;      // consecutive blocks share the A-tile
  int blkM = mt * 128, blkN = nt * 64;
  int wr = widx >> 1, wc = widx & 1;
  int lr = lane & 15, lg = lane >> 4;
  int srow = lane >> 3, scol = (lane & 7) * 8;

  const unsigned short* Ag = A + (size_t)(blkM + widx * 32 + srow) * 512 + scol;
  const unsigned short* Bg = Wt + (size_t)(blkN + widx * 16 + srow) * 512 + scol;
  unsigned short* Al = &Alds[(widx * 32) * 64];
  unsigned short* Bl = &Blds[(widx * 16) * 64];

  f32x4 acc[4][2] = {};

  for (int kc = 0; kc < 512; kc += 64) {
#pragma unroll
    for (int i = 0; i < 4; ++i)
      gload_lds16(Ag + (size_t)(i * 8) * 512 + kc, Al + (i * 8) * 64);
#pragma unroll
    for (int i = 0; i < 2; ++i)
      gload_lds16(Bg + (size_t)(i * 8) * 512 + kc, Bl + (i * 8) * 64);
    __syncthreads();

#pragma unroll
    for (int kh = 0; kh < 2; ++kh) {
      bf16x8 bfr[2];
#pragma unroll
      for (int ni = 0; ni < 2; ++ni)
        bfr[ni] = *(const bf16x8*)&Blds[(wc * 32 + ni * 16 + lr) * 64 + kh * 32 + lg * 8];
#pragma unroll
      for (int mi = 0; mi < 4; ++mi) {
        bf16x8 afr = *(const bf16x8*)&Alds[(wr * 64 + mi * 16 + lr) * 64 + kh * 32 + lg * 8];
#pragma unroll
        for (int ni = 0; ni < 2; ++ni)
          acc[mi][ni] = __builtin_amdgcn_mfma_f32_16x16x32_bf16(afr, bfr[ni], acc[mi][ni], 0, 0, 0);
      }
    }
    __syncthreads();
  }

  int cg = blkN >> 9;                    // 0=Q,1=K,2=V — uniform per block
#pragma unroll
  for (int mi = 0; mi < 4; ++mi)
#pragma unroll
    for (int ni = 0; ni < 2; ++ni) {
      int col = blkN + wc * 32 + ni * 16 + lr;
      int c = col & 511;
#pragma unroll
      for (int j = 0; j < 4; ++j) {
        int row = blkM + wr * 64 + mi * 16 + lg * 4 + j;
        float v = acc[mi][ni][j];
        if (cg == 0) {
          Qo[(size_t)row * 512 + c] = f2bf(v);
        } else if (cg == 1) {
          Ko[(size_t)row * 512 + c] = f2bf(v);
        } else {
          int bb = row >> 11, n = row & 2047, h = c >> 6, d = c & 63;
          // key-slot permutation within each 32-key block so attn's post-softmax
          // P (packed straight from QK^T C-layout) is a valid 16x16x32 B-fragment
          int j5 = n & 31;
          int slot = ((j5 >> 2) & 3) * 8 + ((j5 >> 4) & 1) * 4 + (j5 & 3);
          int np = (n & ~31) | slot;
          Vo[(((size_t)(bb * HEADS + h) * DH + d) << 11) + np] = f2bf(v);
        }
      }
    }
}

// ---------------- Wo GEMM: fp32 out + bias (m97-style, BM=128 BN=64) ----------------
__global__ __launch_bounds__(256, 2) void gemm_out_kernel(
    const unsigned short* __restrict__ A, const unsigned short* __restrict__ Wt,
    float* __restrict__ out, const float* __restrict__ bias) {
  __shared__ unsigned short Alds[128 * 64];
  __shared__ unsigned short Blds[64 * 64];
  int widx = threadIdx.x >> 6, lane = threadIdx.x & 63;
  int blk = blockIdx.x;
  int nt = blk & 7, mt = blk >> 3;
  int blkM = mt * 128, blkN = nt * 64;
  int wr = widx >> 1, wc = widx & 1;
  int lr = lane & 15, lg = lane >> 4;
  int srow = lane >> 3, scol = (lane & 7) * 8;

  const unsigned short* Ag = A + (size_t)(blkM + widx * 32 + srow) * 512 + scol;
  const unsigned short* Bg = Wt + (size_t)(blkN + widx * 16 + srow) * 512 + scol;
  unsigned short* Al = &Alds[(widx * 32) * 64];
  unsigned short* Bl = &Blds[(widx * 16) * 64];

  f32x4 acc[4][2] = {};

  for (int kc = 0; kc < 512; kc += 64) {
#pragma unroll
    for (int i = 0; i < 4; ++i)
      gload_lds16(Ag + (size_t)(i * 8) * 512 + kc, Al + (i * 8) * 64);
#pragma unroll
    for (int i = 0; i < 2; ++i)
      gload_lds16(Bg + (size_t)(i * 8) * 512 + kc, Bl + (i * 8) * 64);
    __syncthreads();

#pragma unroll
    for (int kh = 0; kh < 2; ++kh) {
      bf16x8 bfr[2];
#pragma unroll
      for (int ni = 0; ni < 2; ++ni)
        bfr[ni] = *(const bf16x8*)&Blds[(wc * 32 + ni * 16 + lr) * 64 + kh * 32 + lg * 8];
#pragma unroll
      for (int mi = 0; mi < 4; ++mi) {
        bf16x8 afr = *(const bf16x8*)&Alds[(wr * 64 + mi * 16 + lr) * 64 + kh * 32 + lg * 8];
#pragma unroll
        for (int ni = 0; ni < 2; ++ni)
          acc[mi][ni] = __builtin_amdgcn_mfma_f32_16x16x32_bf16(afr, bfr[ni], acc[mi][ni], 0, 0, 0);
      }
    }
    __syncthreads();
  }

#pragma unroll
  for (int mi = 0; mi < 4; ++mi)
#pragma unroll
    for (int ni = 0; ni < 2; ++ni) {
      int col = blkN + wc * 32 + ni * 16 + lr;
#pragma unroll
      for (int j = 0; j < 4; ++j) {
        int row = blkM + wr * 64 + mi * 16 + lg * 4 + j;
        out[(size_t)row * 512 + col] = acc[mi][ni][j] + bias[col];
      }
    }
}

// ---------------- flash attention, swapped-QK / permuted-V ----------------
// Block = 4 waves sharing one (b,h), each wave owns 16 q-rows; 1024 blocks ->
// 4 blocks/CU. K/V tiles (64 keys) staged in LDS, double-buffered,
// global_load_lds with XOR-swizzled source (rule #21). ONE softmax update per
// 64-key chunk (merged from 2x32); setprio(1) around MFMA clusters (T5).

#define KVCHUNK 64
#define NCHUNK (NSEQ / KVCHUNK)   // 32

#define STAGE(buf, kcc) do {                                              \
    _Pragma("unroll")                                                     \
    for (int i = 0; i < 2; ++i) {                                         \
      int rb = widx * 16 + i * 8;                                         \
      int row = rb + (lane >> 3);                                         \
      int csrc = (lane & 7) ^ (row & 7);                                  \
      gload_lds16(Kg + (size_t)((kcc) + row) * 512 + csrc * 8, &Klds[buf][rb * 64]); \
      gload_lds16(Vg + (size_t)row * NSEQ + (kcc) + csrc * 8, &Vlds[buf][rb * 64]); \
    }                                                                     \
  } while (0)

// process all 64 keys of the staged tile with a single softmax update
#define PROCESS_LDS64(kb_, vb_) do {                                      \
    f32x4 s[4];                                                           \
    __builtin_amdgcn_s_setprio(1);                                        \
    _Pragma("unroll")                                                     \
    for (int kt = 0; kt < 4; ++kt) {                                      \
      int row = kt * 16 + lr;                                             \
      bf16x8 k0 = *(const bf16x8*)((kb_) + row * 64 + ((lg ^ (row & 7)) * 8));       \
      bf16x8 k1 = *(const bf16x8*)((kb_) + row * 64 + (((4 + lg) ^ (row & 7)) * 8)); \
      f32x4 z = {};                                                       \
      z = __builtin_amdgcn_mfma_f32_16x16x32_bf16(k0, qf[0], z, 0, 0, 0); \
      s[kt] = __builtin_amdgcn_mfma_f32_16x16x32_bf16(k1, qf[1], z, 0, 0, 0); \
    }                                                                     \
    __builtin_amdgcn_s_setprio(0);                                        \
    float tt[16];                                                         \
    _Pragma("unroll")                                                     \
    for (int kt = 0; kt < 4; ++kt)                                        \
      _Pragma("unroll")                                                   \
      for (int j = 0; j < 4; ++j) tt[kt * 4 + j] = s[kt][j] * SCALE_L2E;  \
    float m8 = tt[0];                                                     \
    _Pragma("unroll")                                                     \
    for (int i = 1; i < 16; ++i) m8 = fmaxf(m8, tt[i]);                   \
    m8 = fmaxf(m8, __shfl_xor(m8, 16));                                   \
    m8 = fmaxf(m8, __shfl_xor(m8, 32));                                   \
    bool grow = (m8 > m0 + DEFER_THR);                                    \
    if (__any((int)grow)) {                                               \
      float mn = fmaxf(m0, m8);                                           \
      float al = fexp2(m0 - mn);                                          \
      m0 = mn; l0 *= al;                                                  \
      _Pragma("unroll")                                                   \
      for (int dt = 0; dt < 4; ++dt)                                      \
        _Pragma("unroll")                                                 \
        for (int j = 0; j < 4; ++j) o[dt][j] *= al;                       \
    }                                                                     \
    float p[16]; float rs = 0.f;                                          \
    _Pragma("unroll")                                                     \
    for (int i = 0; i < 16; ++i) { p[i] = fexp2(tt[i] - m0); rs += p[i]; }\
    rs += __shfl_xor(rs, 16);                                             \
    rs += __shfl_xor(rs, 32);                                             \
    l0 += rs;                                                             \
    union { unsigned w[4]; bf16x8 v; } pf0, pf1;                          \
    _Pragma("unroll")                                                     \
    for (int d2 = 0; d2 < 4; ++d2) {                                      \
      pf0.w[d2] = cvt_pk_bf16(p[d2 * 2], p[d2 * 2 + 1]);                  \
      pf1.w[d2] = cvt_pk_bf16(p[8 + d2 * 2], p[8 + d2 * 2 + 1]);          \
    }                                                                     \
    __builtin_amdgcn_s_setprio(1);                                        \
    _Pragma("unroll")                                                     \
    for (int dt = 0; dt < 4; ++dt) {                                      \
      int row = dt * 16 + lr;                                             \
      bf16x8 v0 = *(const bf16x8*)((vb_) + row * 64 + ((lg ^ (row & 7)) * 8));       \
      bf16x8 v1 = *(const bf16x8*)((vb_) + row * 64 + (((4 + lg) ^ (row & 7)) * 8)); \
      o[dt] = __builtin_amdgcn_mfma_f32_16x16x32_bf16(v0, pf0.v, o[dt], 0, 0, 0);    \
      o[dt] = __builtin_amdgcn_mfma_f32_16x16x32_bf16(v1, pf1.v, o[dt], 0, 0, 0);    \
    }                                                                     \
    __builtin_amdgcn_s_setprio(0);                                        \
  } while (0)

__global__ __launch_bounds__(256, 4) void attn_kernel(
    const unsigned short* __restrict__ Q, const unsigned short* __restrict__ K,
    const unsigned short* __restrict__ VT, unsigned short* __restrict__ O) {
  __shared__ unsigned short Klds[2][64 * 64];
  __shared__ unsigned short Vlds[2][64 * 64];
  int widx = threadIdx.x >> 6, lane = threadIdx.x & 63;
  int blk = blockIdx.x;                // 0..1023
  int xcd = blk & 7;
  int idx = blk >> 3;                  // 0..127 within XCD
  int bh = xcd * 4 + (idx >> 5);       // 0..31 (4 bh per XCD; all 4 waves share bh)
  int qg = idx & 31;                   // 64-row q-group within bh
  int b = bh >> 3, h = bh & 7;
  int lr = lane & 15, lg = lane >> 4;
  int qrow0 = qg * 64 + widx * 16;     // this wave's 16 q-rows

  const size_t qk_base = (size_t)b * NSEQ * 512 + h * 64 + lg * 8;
  bf16x8 qf[2];
  {
    size_t qa = qk_base + (size_t)(qrow0 + lr) * 512;
    qf[0] = *(const bf16x8*)(Q + qa);
    qf[1] = *(const bf16x8*)(Q + qa + 32);
  }
  const unsigned short* Kg = K + (size_t)b * NSEQ * 512 + h * 64;
  const unsigned short* Vg = VT + (size_t)bh * DH * NSEQ;

  float m0 = -3.0e38f;
  float l0 = 0.f;
  f32x4 o[4] = {};

  STAGE(0, 0);
  __syncthreads();
  int cur = 0;
  for (int t = 0; t < NCHUNK; ++t) {
    if (t + 1 < NCHUNK) STAGE(cur ^ 1, (t + 1) * KVCHUNK);
    const unsigned short* kb_ = &Klds[cur][0];
    const unsigned short* vb_ = &Vlds[cur][0];
    PROCESS_LDS64(kb_, vb_);
    __syncthreads();   // drains next-tile staging; guards LDS reuse
    cur ^= 1;
  }

  {
    float inv = 1.f / l0;
    size_t row = (size_t)(b * NSEQ + qrow0 + lr) * 512 + h * 64 + lg * 4;
#pragma unroll
    for (int dt = 0; dt < 4; ++dt) {
      unsigned w0 = cvt_pk_bf16(o[dt][0] * inv, o[dt][1] * inv);
      unsigned w1 = cvt_pk_bf16(o[dt][2] * inv, o[dt][3] * inv);
      uint2 st = {w0, w1};
      *(uint2*)(O + row + dt * 16) = st;
    }
  }
}

extern "C" void kernel_launch(void* const* d_in, const int* in_sizes, int n_in,
                              void* d_out, int out_size, void* d_ws, size_t ws_size,
                              hipStream_t stream) {
  const float* x   = (const float*)d_in[0];
  const float* z   = (const float*)d_in[1];
  const float* lxg = (const float*)d_in[2];
  const float* lxb = (const float*)d_in[3];
  const float* lzg = (const float*)d_in[4];
  const float* lzb = (const float*)d_in[5];
  const float* Wq  = (const float*)d_in[6];
  const float* Wk  = (const float*)d_in[7];
  const float* Wv  = (const float*)d_in[8];
  const float* Wz  = (const float*)d_in[9];
  const float* Wo  = (const float*)d_in[10];
  const float* bo  = (const float*)d_in[11];

  char* ws = (char*)d_ws;
  unsigned short* xm  = (unsigned short*)(ws);
  unsigned short* qb  = (unsigned short*)(ws + 8388608);
  unsigned short* kb  = (unsigned short*)(ws + 16777216);
  unsigned short* vt  = (unsigned short*)(ws + 25165824);
  unsigned short* ao  = (unsigned short*)(ws + 33554432);
  unsigned short* wqt = (unsigned short*)(ws + 41943040);   // wq,wk,wv,wo contiguous
  unsigned short* wot = (unsigned short*)(ws + 43515904);
  float*          z12 = (float*)(ws + 44040192);

  zpath_kernel<<<NBATCH, 256, 0, stream>>>(z, lzg, lzb, Wz, z12);
  xmod_kernel<<<NROWS / 4, 256, 0, stream>>>(x, lxg, lxb, z12, xm);
  wtrans4_kernel<<<4096, 256, 0, stream>>>(Wq, Wk, Wv, Wo, wqt);
  gemm_qkv_kernel<<<1536, 256, 0, stream>>>(xm, wqt, qb, kb, vt);
  attn_kernel<<<1024, 256, 0, stream>>>(qb, kb, vt, ao);
  gemm_out_kernel<<<512, 256, 0, stream>>>(ao, wot, (float*)d_out, bo);
}

// Round 9
// 115.850 us; speedup vs baseline: 3.5441x; 1.0461x over previous
//
#include <hip/hip_runtime.h>

#define XD 512
#define HEADS 8
#define DH 64
#define NSEQ 2048
#define NBATCH 4
#define NROWS (NBATCH*NSEQ)   // 8192

#define SCALE_L2E 0.18033688011112042f   // 0.125 * log2(e)
#define DEFER_THR 4.0f

typedef __attribute__((ext_vector_type(8))) short bf16x8;
typedef __attribute__((ext_vector_type(8))) unsigned short u16x8;
typedef __attribute__((ext_vector_type(4))) float f32x4;
typedef __attribute__((ext_vector_type(16))) float f32x16;

__device__ __forceinline__ unsigned short f2bf(float f) {
  union { float f; unsigned u; } v; v.f = f;
  return (unsigned short)((v.u + 0x7fffu + ((v.u >> 16) & 1u)) >> 16);
}

__device__ __forceinline__ float fexp2(float x) {
#if __has_builtin(__builtin_amdgcn_exp2f)
  return __builtin_amdgcn_exp2f(x);
#else
  return exp2f(x);
#endif
}

__device__ __forceinline__ unsigned cvt_pk_bf16(float lo, float hi) {
  unsigned r;
  asm("v_cvt_pk_bf16_f32 %0, %1, %2" : "=v"(r) : "v"(lo), "v"(hi));
  return r;
}

// async global->LDS, 16B per lane; LDS dest must be wave-uniform base (HW adds lane*16)
__device__ __forceinline__ void gload_lds16(const unsigned short* g, unsigned short* l) {
  __builtin_amdgcn_global_load_lds(
      (const __attribute__((address_space(1))) unsigned int*)g,
      (__attribute__((address_space(3))) unsigned int*)l, 16, 0, 0);
}

// ---------------- z path: LN(z) @ Wz -> silu -> z1,z2  (tiny) ----------------
__global__ __launch_bounds__(256) void zpath_kernel(
    const float* __restrict__ z, const float* __restrict__ g, const float* __restrict__ b,
    const float* __restrict__ Wz, float* __restrict__ z12) {
  int bb = blockIdx.x;            // batch
  int t = threadIdx.x;
  float zv[16];
  float mean = 0.f;
#pragma unroll
  for (int i = 0; i < 16; ++i) { zv[i] = z[bb * 16 + i]; mean += zv[i]; }
  mean *= (1.f / 16.f);
  float var = 0.f;
#pragma unroll
  for (int i = 0; i < 16; ++i) { float d = zv[i] - mean; var += d * d; }
  var *= (1.f / 16.f);
  float rs = rsqrtf(var + 1e-5f);
  float zn[16];
#pragma unroll
  for (int i = 0; i < 16; ++i) zn[i] = (zv[i] - mean) * rs * g[i] + b[i];
  for (int c = t; c < 1024; c += 256) {
    float acc = 0.f;
#pragma unroll
    for (int i = 0; i < 16; ++i) acc += zn[i] * Wz[i * 1024 + c];
    float s = acc / (1.f + __expf(-acc));   // silu
    z12[bb * 1024 + c] = s;
  }
}

// ---------------- x_mod = LN(x)*z1 + z2 -> bf16 [8192,512] ----------------
__global__ __launch_bounds__(256) void xmod_kernel(
    const float* __restrict__ x, const float* __restrict__ g, const float* __restrict__ b,
    const float* __restrict__ z12, unsigned short* __restrict__ xm) {
  int wave = threadIdx.x >> 6, lane = threadIdx.x & 63;
  int row = blockIdx.x * 4 + wave;
  const float* xr = x + (size_t)row * XD;
  float4 v0 = ((const float4*)xr)[lane * 2];
  float4 v1 = ((const float4*)xr)[lane * 2 + 1];
  float vv[8] = {v0.x, v0.y, v0.z, v0.w, v1.x, v1.y, v1.z, v1.w};
  float sum = 0.f, sq = 0.f;
#pragma unroll
  for (int i = 0; i < 8; ++i) { sum += vv[i]; sq += vv[i] * vv[i]; }
#pragma unroll
  for (int o = 32; o; o >>= 1) { sum += __shfl_xor(sum, o); sq += __shfl_xor(sq, o); }
  float mean = sum * (1.f / 512.f);
  float var = sq * (1.f / 512.f) - mean * mean;
  float rs = rsqrtf(var + 1e-5f);
  int bb = row >> 11;
  const float* zz = z12 + bb * 1024;
  int c0 = lane * 8;
  u16x8 o8;
#pragma unroll
  for (int i = 0; i < 8; ++i) {
    int c = c0 + i;
    float t = (vv[i] - mean) * rs * g[c] + b[c];
    t = t * zz[c] + zz[512 + c];
    o8[i] = f2bf(t);
  }
  *(u16x8*)(xm + (size_t)row * XD + c0) = o8;
}

// ------- fused weight transpose fp32[K,N] -> bf16 [n][k] for Wq,Wk,Wv,Wo -------
__global__ __launch_bounds__(256) void wtrans4_kernel(
    const float* __restrict__ W0, const float* __restrict__ W1,
    const float* __restrict__ W2, const float* __restrict__ W3,
    unsigned short* __restrict__ dst) {
  int idx = blockIdx.x * 256 + threadIdx.x;   // 0..1048575
  int w = idx >> 18;                           // which weight (block-uniform)
  int e = idx & 262143;                        // n*512 + k
  int n = e >> 9, k = e & 511;
  const float* W = (w == 0) ? W0 : (w == 1) ? W1 : (w == 2) ? W2 : W3;
  dst[idx] = f2bf(W[k * 512 + n]);
}

// ---------- fused QKV GEMM: [8192,512] @ [512,1536] (Wt contiguous [n][k]) ----------
// BM=128, BN=64, BK=64; grid 64 mt x 24 nt. Per-block-uniform epilogue by col>>9:
// 0 -> Q bf16 row-major PRE-SCALED by 0.125*log2e, 1 -> K bf16 row-major,
// 2 -> V per-head-transposed with 16-key-group slot permutation (swap bits 2,3)
//      so attn's P (packed from the 32x32 QK^T C-layout) is a valid B-fragment.
__global__ __launch_bounds__(256, 2) void gemm_qkv_kernel(
    const unsigned short* __restrict__ A, const unsigned short* __restrict__ Wt,
    unsigned short* __restrict__ Qo, unsigned short* __restrict__ Ko,
    unsigned short* __restrict__ Vo) {
  __shared__ unsigned short Alds[128 * 64];
  __shared__ unsigned short Blds[64 * 64];
  int widx = threadIdx.x >> 6, lane = threadIdx.x & 63;
  int blk = blockIdx.x;
  int nt = blk % 24, mt = blk / 24;      // consecutive blocks share the A-tile
  int blkM = mt * 128, blkN = nt * 64;
  int wr = widx >> 1, wc = widx & 1;
  int lr = lane & 15, lg = lane >> 4;
  int srow = lane >> 3, scol = (lane & 7) * 8;

  const unsigned short* Ag = A + (size_t)(blkM + widx * 32 + srow) * 512 + scol;
  const unsigned short* Bg = Wt + (size_t)(blkN + widx * 16 + srow) * 512 + scol;
  unsigned short* Al = &Alds[(widx * 32) * 64];
  unsigned short* Bl = &Blds[(widx * 16) * 64];

  f32x4 acc[4][2] = {};

  for (int kc = 0; kc < 512; kc += 64) {
#pragma unroll
    for (int i = 0; i < 4; ++i)
      gload_lds16(Ag + (size_t)(i * 8) * 512 + kc, Al + (i * 8) * 64);
#pragma unroll
    for (int i = 0; i < 2; ++i)
      gload_lds16(Bg + (size_t)(i * 8) * 512 + kc, Bl + (i * 8) * 64);
    __syncthreads();

#pragma unroll
    for (int kh = 0; kh < 2; ++kh) {
      bf16x8 bfr[2];
#pragma unroll
      for (int ni = 0; ni < 2; ++ni)
        bfr[ni] = *(const bf16x8*)&Blds[(wc * 32 + ni * 16 + lr) * 64 + kh * 32 + lg * 8];
#pragma unroll
      for (int mi = 0; mi < 4; ++mi) {
        bf16x8 afr = *(const bf16x8*)&Alds[(wr * 64 + mi * 16 + lr) * 64 + kh * 32 + lg * 8];
#pragma unroll
        for (int ni = 0; ni < 2; ++ni)
          acc[mi][ni] = __builtin_amdgcn_mfma_f32_16x16x32_bf16(afr, bfr[ni], acc[mi][ni], 0, 0, 0);
      }
    }
    __syncthreads();
  }

  int cg = blkN >> 9;                    // 0=Q,1=K,2=V — uniform per block
#pragma unroll
  for (int mi = 0; mi < 4; ++mi)
#pragma unroll
    for (int ni = 0; ni < 2; ++ni) {
      int col = blkN + wc * 32 + ni * 16 + lr;
      int c = col & 511;
#pragma unroll
      for (int j = 0; j < 4; ++j) {
        int row = blkM + wr * 64 + mi * 16 + lg * 4 + j;
        float v = acc[mi][ni][j];
        if (cg == 0) {
          Qo[(size_t)row * 512 + c] = f2bf(v * SCALE_L2E);
        } else if (cg == 1) {
          Ko[(size_t)row * 512 + c] = f2bf(v);
        } else {
          int bb = row >> 11, n = row & 2047, h = c >> 6, d = c & 63;
          // slot(key) within each 16-key group = swap bits 2 and 3
          int j4 = n & 15;
          int slot = (j4 & 3) | (((j4 >> 3) & 1) << 2) | (((j4 >> 2) & 1) << 3);
          int np = (n & ~15) | slot;
          Vo[(((size_t)(bb * HEADS + h) * DH + d) << 11) + np] = f2bf(v);
        }
      }
    }
}

// ---------------- Wo GEMM: fp32 out + bias (m97-style, BM=128 BN=64) ----------------
__global__ __launch_bounds__(256, 2) void gemm_out_kernel(
    const unsigned short* __restrict__ A, const unsigned short* __restrict__ Wt,
    float* __restrict__ out, const float* __restrict__ bias) {
  __shared__ unsigned short Alds[128 * 64];
  __shared__ unsigned short Blds[64 * 64];
  int widx = threadIdx.x >> 6, lane = threadIdx.x & 63;
  int blk = blockIdx.x;
  int nt = blk & 7, mt = blk >> 3;
  int blkM = mt * 128, blkN = nt * 64;
  int wr = widx >> 1, wc = widx & 1;
  int lr = lane & 15, lg = lane >> 4;
  int srow = lane >> 3, scol = (lane & 7) * 8;

  const unsigned short* Ag = A + (size_t)(blkM + widx * 32 + srow) * 512 + scol;
  const unsigned short* Bg = Wt + (size_t)(blkN + widx * 16 + srow) * 512 + scol;
  unsigned short* Al = &Alds[(widx * 32) * 64];
  unsigned short* Bl = &Blds[(widx * 16) * 64];

  f32x4 acc[4][2] = {};

  for (int kc = 0; kc < 512; kc += 64) {
#pragma unroll
    for (int i = 0; i < 4; ++i)
      gload_lds16(Ag + (size_t)(i * 8) * 512 + kc, Al + (i * 8) * 64);
#pragma unroll
    for (int i = 0; i < 2; ++i)
      gload_lds16(Bg + (size_t)(i * 8) * 512 + kc, Bl + (i * 8) * 64);
    __syncthreads();

#pragma unroll
    for (int kh = 0; kh < 2; ++kh) {
      bf16x8 bfr[2];
#pragma unroll
      for (int ni = 0; ni < 2; ++ni)
        bfr[ni] = *(const bf16x8*)&Blds[(wc * 32 + ni * 16 + lr) * 64 + kh * 32 + lg * 8];
#pragma unroll
      for (int mi = 0; mi < 4; ++mi) {
        bf16x8 afr = *(const bf16x8*)&Alds[(wr * 64 + mi * 16 + lr) * 64 + kh * 32 + lg * 8];
#pragma unroll
        for (int ni = 0; ni < 2; ++ni)
          acc[mi][ni] = __builtin_amdgcn_mfma_f32_16x16x32_bf16(afr, bfr[ni], acc[mi][ni], 0, 0, 0);
      }
    }
    __syncthreads();
  }

#pragma unroll
  for (int mi = 0; mi < 4; ++mi)
#pragma unroll
    for (int ni = 0; ni < 2; ++ni) {
      int col = blkN + wc * 32 + ni * 16 + lr;
#pragma unroll
      for (int j = 0; j < 4; ++j) {
        int row = blkM + wr * 64 + mi * 16 + lg * 4 + j;
        out[(size_t)row * 512 + col] = acc[mi][ni][j] + bias[col];
      }
    }
}

// ---------------- flash attention, 32x32 MFMA, swapped-QK / slot-permuted V ----------
// Block = 4 waves sharing one (b,h), each wave owns 32 q-rows. 512 blocks ->
// 2 blocks/CU. K/V (64-key chunks) staged in LDS double-buffered via
// global_load_lds with XOR-swizzled source (rule #21). Q pre-scaled, so scores
// are already in the exp2 domain.
// Layouts (32x32x16): A row=lane&31, k=(lane>>5)*8+j ; B col=lane&31, same k;
// C col=lane&31, row=(r&3)+8*(r>>2)+4*(lane>>5).

#define KVCHUNK 64
#define NCHUNK (NSEQ / KVCHUNK)   // 32

#define STAGE(buf, kcc) do {                                              \
    _Pragma("unroll")                                                     \
    for (int i = 0; i < 2; ++i) {                                         \
      int rb = widx * 16 + i * 8;                                         \
      int row = rb + (lane >> 3);                                         \
      int csrc = (lane & 7) ^ (row & 7);                                  \
      gload_lds16(Kg + (size_t)((kcc) + row) * 512 + csrc * 8, &Klds[buf][rb * 64]); \
      gload_lds16(Vg + (size_t)row * NSEQ + (kcc) + csrc * 8, &Vlds[buf][rb * 64]); \
    }                                                                     \
  } while (0)

__global__ __launch_bounds__(256, 2) void attn_kernel(
    const unsigned short* __restrict__ Q, const unsigned short* __restrict__ K,
    const unsigned short* __restrict__ VT, unsigned short* __restrict__ O) {
  __shared__ unsigned short Klds[2][64 * 64];
  __shared__ unsigned short Vlds[2][64 * 64];
  int widx = threadIdx.x >> 6, lane = threadIdx.x & 63;
  int blk = blockIdx.x;                // 0..511
  int xcd = blk & 7;
  int idx = blk >> 3;                  // 0..63 within XCD
  int bh = xcd * 4 + (idx >> 4);       // 0..31 (4 bh per XCD; all 4 waves share bh)
  int qg = idx & 15;                   // 128-row q-group within bh
  int b = bh >> 3, h = bh & 7;
  int ql = lane & 31, hi = lane >> 5;
  int qrow0 = qg * 128 + widx * 32;    // this wave's 32 q-rows

  // Q B-fragments: col q = ql, k-slice ks: d = ks*16 + hi*8 + j (pre-scaled)
  bf16x8 qf[4];
  const unsigned short* Qp = Q + (size_t)(b * NSEQ + qrow0 + ql) * 512 + h * 64 + hi * 8;
#pragma unroll
  for (int ks = 0; ks < 4; ++ks) qf[ks] = *(const bf16x8*)(Qp + ks * 16);

  const unsigned short* Kg = K + (size_t)b * NSEQ * 512 + h * 64;
  const unsigned short* Vg = VT + (size_t)bh * DH * NSEQ;

  float m0 = -3.0e38f, l0 = 0.f;
  f32x16 o[2] = {};

  STAGE(0, 0);
  __syncthreads();
  int cur = 0;
  for (int t = 0; t < NCHUNK; ++t) {
    if (t + 1 < NCHUNK) STAGE(cur ^ 1, (t + 1) * KVCHUNK);
    const unsigned short* kb_ = &Klds[cur][0];
    const unsigned short* vb_ = &Vlds[cur][0];

    // QK^T: S^T[key][q] for 64 keys; lane holds q=ql, keys (r&3)+8(r>>2)+4hi per tile
    f32x16 s[2];
    __builtin_amdgcn_s_setprio(1);
#pragma unroll
    for (int kt = 0; kt < 2; ++kt) {
      int krow = kt * 32 + ql;
      f32x16 z = {};
#pragma unroll
      for (int ks = 0; ks < 4; ++ks) {
        bf16x8 kf = *(const bf16x8*)(kb_ + krow * 64 + (((ks * 2 + hi) ^ (krow & 7)) * 8));
        z = __builtin_amdgcn_mfma_f32_32x32x16_bf16(kf, qf[ks], z, 0, 0, 0);
      }
      s[kt] = z;
    }
    __builtin_amdgcn_s_setprio(0);

    // online softmax over 32 scores/lane (already log2-domain)
    float m8 = s[0][0];
#pragma unroll
    for (int i = 1; i < 16; ++i) m8 = fmaxf(m8, s[0][i]);
#pragma unroll
    for (int i = 0; i < 16; ++i) m8 = fmaxf(m8, s[1][i]);
    m8 = fmaxf(m8, __shfl_xor(m8, 32));
    bool grow = (m8 > m0 + DEFER_THR);
    if (__any((int)grow)) {
      float mn = fmaxf(m0, m8);
      float al = fexp2(m0 - mn);
      m0 = mn; l0 *= al;
#pragma unroll
      for (int dt = 0; dt < 2; ++dt)
#pragma unroll
        for (int j = 0; j < 16; ++j) o[dt][j] *= al;
    }
    float p0[16], p1[16]; float rs = 0.f;
#pragma unroll
    for (int i = 0; i < 16; ++i) { p0[i] = fexp2(s[0][i] - m0); rs += p0[i]; }
#pragma unroll
    for (int i = 0; i < 16; ++i) { p1[i] = fexp2(s[1][i] - m0); rs += p1[i]; }
    rs += __shfl_xor(rs, 32);
    l0 += rs;

    // pack P into 4 B-fragments (16-key groups); V slot permutation makes these line up
    union { unsigned w[4]; bf16x8 v; } pf[4];
#pragma unroll
    for (int d2 = 0; d2 < 4; ++d2) {
      pf[0].w[d2] = cvt_pk_bf16(p0[2 * d2], p0[2 * d2 + 1]);
      pf[1].w[d2] = cvt_pk_bf16(p0[8 + 2 * d2], p0[8 + 2 * d2 + 1]);
      pf[2].w[d2] = cvt_pk_bf16(p1[2 * d2], p1[2 * d2 + 1]);
      pf[3].w[d2] = cvt_pk_bf16(p1[8 + 2 * d2], p1[8 + 2 * d2 + 1]);
    }

    // PV: O[d][q] += V[d][slot] * P[slot][q]
    __builtin_amdgcn_s_setprio(1);
#pragma unroll
    for (int dt = 0; dt < 2; ++dt) {
      int vrow = dt * 32 + ql;
      f32x16 acc = o[dt];
#pragma unroll
      for (int g = 0; g < 4; ++g) {
        bf16x8 vf = *(const bf16x8*)(vb_ + vrow * 64 + (((g * 2 + hi) ^ (vrow & 7)) * 8));
        acc = __builtin_amdgcn_mfma_f32_32x32x16_bf16(vf, pf[g].v, acc, 0, 0, 0);
      }
      o[dt] = acc;
    }
    __builtin_amdgcn_s_setprio(0);

    __syncthreads();   // drains next-tile staging; guards LDS reuse
    cur ^= 1;
  }

  // epilogue: C layout row d=(r&3)+8(r>>2)+4hi, col q=ql
  {
    float inv = 1.f / l0;
    size_t rowb = (size_t)(b * NSEQ + qrow0 + ql) * 512 + h * 64 + hi * 4;
#pragma unroll
    for (int dt = 0; dt < 2; ++dt)
#pragma unroll
      for (int c = 0; c < 8; ++c) {
        unsigned w = cvt_pk_bf16(o[dt][2 * c] * inv, o[dt][2 * c + 1] * inv);
        int d0 = dt * 32 + 8 * (c >> 1) + (c & 1) * 2;
        *(unsigned*)(O + rowb + d0) = w;
      }
  }
}

extern "C" void kernel_launch(void* const* d_in, const int* in_sizes, int n_in,
                              void* d_out, int out_size, void* d_ws, size_t ws_size,
                              hipStream_t stream) {
  const float* x   = (const float*)d_in[0];
  const float* z   = (const float*)d_in[1];
  const float* lxg = (const float*)d_in[2];
  const float* lxb = (const float*)d_in[3];
  const float* lzg = (const float*)d_in[4];
  const float* lzb = (const float*)d_in[5];
  const float* Wq  = (const float*)d_in[6];
  const float* Wk  = (const float*)d_in[7];
  const float* Wv  = (const float*)d_in[8];
  const float* Wz  = (const float*)d_in[9];
  const float* Wo  = (const float*)d_in[10];
  const float* bo  = (const float*)d_in[11];

  char* ws = (char*)d_ws;
  unsigned short* xm  = (unsigned short*)(ws);
  unsigned short* qb  = (unsigned short*)(ws + 8388608);
  unsigned short* kb  = (unsigned short*)(ws + 16777216);
  unsigned short* vt  = (unsigned short*)(ws + 25165824);
  unsigned short* ao  = (unsigned short*)(ws + 33554432);
  unsigned short* wqt = (unsigned short*)(ws + 41943040);   // wq,wk,wv,wo contiguous
  unsigned short* wot = (unsigned short*)(ws + 43515904);
  float*          z12 = (float*)(ws + 44040192);

  zpath_kernel<<<NBATCH, 256, 0, stream>>>(z, lzg, lzb, Wz, z12);
  xmod_kernel<<<NROWS / 4, 256, 0, stream>>>(x, lxg, lxb, z12, xm);
  wtrans4_kernel<<<4096, 256, 0, stream>>>(Wq, Wk, Wv, Wo, wqt);
  gemm_qkv_kernel<<<1536, 256, 0, stream>>>(xm, wqt, qb, kb, vt);
  attn_kernel<<<512, 256, 0, stream>>>(qb, kb, vt, ao);
  gemm_out_kernel<<<512, 256, 0, stream>>>(ao, wot, (float*)d_out, bo);
}

// Round 10
// 111.442 us; speedup vs baseline: 3.6843x; 1.0396x over previous
//
#include <hip/hip_runtime.h>

#define XD 512
#define HEADS 8
#define DH 64
#define NSEQ 2048
#define NBATCH 4
#define NROWS (NBATCH*NSEQ)   // 8192

#define SCALE_L2E 0.18033688011112042f   // 0.125 * log2(e)
#define DEFER_THR 4.0f

typedef __attribute__((ext_vector_type(8))) short bf16x8;
typedef __attribute__((ext_vector_type(8))) unsigned short u16x8;
typedef __attribute__((ext_vector_type(4))) float f32x4;
typedef __attribute__((ext_vector_type(16))) float f32x16;

__device__ __forceinline__ unsigned short f2bf(float f) {
  union { float f; unsigned u; } v; v.f = f;
  return (unsigned short)((v.u + 0x7fffu + ((v.u >> 16) & 1u)) >> 16);
}

__device__ __forceinline__ float fexp2(float x) {
#if __has_builtin(__builtin_amdgcn_exp2f)
  return __builtin_amdgcn_exp2f(x);
#else
  return exp2f(x);
#endif
}

__device__ __forceinline__ unsigned cvt_pk_bf16(float lo, float hi) {
  unsigned r;
  asm("v_cvt_pk_bf16_f32 %0, %1, %2" : "=v"(r) : "v"(lo), "v"(hi));
  return r;
}

// async global->LDS, 16B per lane; LDS dest must be wave-uniform base (HW adds lane*16)
__device__ __forceinline__ void gload_lds16(const unsigned short* g, unsigned short* l) {
  __builtin_amdgcn_global_load_lds(
      (const __attribute__((address_space(1))) unsigned int*)g,
      (__attribute__((address_space(3))) unsigned int*)l, 16, 0, 0);
}

// ---------------- z path: LN(z) @ Wz -> silu -> z1,z2  (tiny) ----------------
__global__ __launch_bounds__(256) void zpath_kernel(
    const float* __restrict__ z, const float* __restrict__ g, const float* __restrict__ b,
    const float* __restrict__ Wz, float* __restrict__ z12) {
  int bb = blockIdx.x;            // batch
  int t = threadIdx.x;
  float zv[16];
  float mean = 0.f;
#pragma unroll
  for (int i = 0; i < 16; ++i) { zv[i] = z[bb * 16 + i]; mean += zv[i]; }
  mean *= (1.f / 16.f);
  float var = 0.f;
#pragma unroll
  for (int i = 0; i < 16; ++i) { float d = zv[i] - mean; var += d * d; }
  var *= (1.f / 16.f);
  float rs = rsqrtf(var + 1e-5f);
  float zn[16];
#pragma unroll
  for (int i = 0; i < 16; ++i) zn[i] = (zv[i] - mean) * rs * g[i] + b[i];
  for (int c = t; c < 1024; c += 256) {
    float acc = 0.f;
#pragma unroll
    for (int i = 0; i < 16; ++i) acc += zn[i] * Wz[i * 1024 + c];
    float s = acc / (1.f + __expf(-acc));   // silu
    z12[bb * 1024 + c] = s;
  }
}

// ---------------- x_mod = LN(x)*z1 + z2 -> bf16 [8192,512] ----------------
__global__ __launch_bounds__(256) void xmod_kernel(
    const float* __restrict__ x, const float* __restrict__ g, const float* __restrict__ b,
    const float* __restrict__ z12, unsigned short* __restrict__ xm) {
  int wave = threadIdx.x >> 6, lane = threadIdx.x & 63;
  int row = blockIdx.x * 4 + wave;
  const float* xr = x + (size_t)row * XD;
  float4 v0 = ((const float4*)xr)[lane * 2];
  float4 v1 = ((const float4*)xr)[lane * 2 + 1];
  float vv[8] = {v0.x, v0.y, v0.z, v0.w, v1.x, v1.y, v1.z, v1.w};
  float sum = 0.f, sq = 0.f;
#pragma unroll
  for (int i = 0; i < 8; ++i) { sum += vv[i]; sq += vv[i] * vv[i]; }
#pragma unroll
  for (int o = 32; o; o >>= 1) { sum += __shfl_xor(sum, o); sq += __shfl_xor(sq, o); }
  float mean = sum * (1.f / 512.f);
  float var = sq * (1.f / 512.f) - mean * mean;
  float rs = rsqrtf(var + 1e-5f);
  int bb = row >> 11;
  const float* zz = z12 + bb * 1024;
  int c0 = lane * 8;
  u16x8 o8;
#pragma unroll
  for (int i = 0; i < 8; ++i) {
    int c = c0 + i;
    float t = (vv[i] - mean) * rs * g[c] + b[c];
    t = t * zz[c] + zz[512 + c];
    o8[i] = f2bf(t);
  }
  *(u16x8*)(xm + (size_t)row * XD + c0) = o8;
}

// ------- fused weight transpose fp32[K,N] -> bf16 [n][k] for Wq,Wk,Wv,Wo -------
__global__ __launch_bounds__(256) void wtrans4_kernel(
    const float* __restrict__ W0, const float* __restrict__ W1,
    const float* __restrict__ W2, const float* __restrict__ W3,
    unsigned short* __restrict__ dst) {
  int idx = blockIdx.x * 256 + threadIdx.x;   // 0..1048575
  int w = idx >> 18;                           // which weight (block-uniform)
  int e = idx & 262143;                        // n*512 + k
  int n = e >> 9, k = e & 511;
  const float* W = (w == 0) ? W0 : (w == 1) ? W1 : (w == 2) ? W2 : W3;
  dst[idx] = f2bf(W[k * 512 + n]);
}

// ---------- fused QKV GEMM: [8192,512] @ [512,1536], BM=128 BN=128 BK=64 ----------
// 4 waves (2x2), each 64x64 out (4x4 frags). XOR slot-swizzled LDS (T2):
// stage source chunk (lane&7)^(row&7); read slot (kh*4+lg)^(row&7). Epilogue by
// blkN>>9: 0 -> Q prescaled, 1 -> K, 2 -> V transposed+slot-permuted.
__global__ __launch_bounds__(256, 2) void gemm_qkv_kernel(
    const unsigned short* __restrict__ A, const unsigned short* __restrict__ Wt,
    unsigned short* __restrict__ Qo, unsigned short* __restrict__ Ko,
    unsigned short* __restrict__ Vo) {
  __shared__ unsigned short Alds[128 * 64];
  __shared__ unsigned short Blds[128 * 64];
  int widx = threadIdx.x >> 6, lane = threadIdx.x & 63;
  int blk = blockIdx.x;
  int nt = blk % 12, mt = blk / 12;      // consecutive blocks share the A-tile
  int blkM = mt * 128, blkN = nt * 128;
  int wr = widx >> 1, wc = widx & 1;
  int lr = lane & 15, lg = lane >> 4;
  int srow = lane >> 3, sc8 = lane & 7;

  f32x4 acc[4][4] = {};

  for (int kc = 0; kc < 512; kc += 64) {
#pragma unroll
    for (int i = 0; i < 4; ++i) {
      int rb = widx * 32 + i * 8;
      int row = rb + srow;
      int cs = (sc8 ^ (row & 7)) * 8;
      gload_lds16(A + (size_t)(blkM + row) * 512 + kc + cs, &Alds[rb * 64]);
      gload_lds16(Wt + (size_t)(blkN + row) * 512 + kc + cs, &Blds[rb * 64]);
    }
    __syncthreads();

#pragma unroll
    for (int kh = 0; kh < 2; ++kh) {
      bf16x8 bfr[4];
#pragma unroll
      for (int ni = 0; ni < 4; ++ni) {
        int brow = wc * 64 + ni * 16 + lr;
        bfr[ni] = *(const bf16x8*)&Blds[brow * 64 + (((kh * 4 + lg) ^ (brow & 7)) * 8)];
      }
#pragma unroll
      for (int mi = 0; mi < 4; ++mi) {
        int arow = wr * 64 + mi * 16 + lr;
        bf16x8 afr = *(const bf16x8*)&Alds[arow * 64 + (((kh * 4 + lg) ^ (arow & 7)) * 8)];
#pragma unroll
        for (int ni = 0; ni < 4; ++ni)
          acc[mi][ni] = __builtin_amdgcn_mfma_f32_16x16x32_bf16(afr, bfr[ni], acc[mi][ni], 0, 0, 0);
      }
    }
    __syncthreads();
  }

  int cg = blkN >> 9;                    // 0=Q,1=K,2=V — uniform per block
#pragma unroll
  for (int mi = 0; mi < 4; ++mi)
#pragma unroll
    for (int ni = 0; ni < 4; ++ni) {
      int col = blkN + wc * 64 + ni * 16 + lr;
      int c = col & 511;
#pragma unroll
      for (int j = 0; j < 4; ++j) {
        int row = blkM + wr * 64 + mi * 16 + lg * 4 + j;
        float v = acc[mi][ni][j];
        if (cg == 0) {
          Qo[(size_t)row * 512 + c] = f2bf(v * SCALE_L2E);
        } else if (cg == 1) {
          Ko[(size_t)row * 512 + c] = f2bf(v);
        } else {
          int bb = row >> 11, n = row & 2047, h = c >> 6, d = c & 63;
          // slot(key) within each 16-key group = swap bits 2 and 3
          int j4 = n & 15;
          int slot = (j4 & 3) | (((j4 >> 3) & 1) << 2) | (((j4 >> 2) & 1) << 3);
          int np = (n & ~15) | slot;
          Vo[(((size_t)(bb * HEADS + h) * DH + d) << 11) + np] = f2bf(v);
        }
      }
    }
}

// ---------------- Wo GEMM: fp32 out + bias (BM=128 BN=64, swizzled LDS) ----------------
__global__ __launch_bounds__(256, 2) void gemm_out_kernel(
    const unsigned short* __restrict__ A, const unsigned short* __restrict__ Wt,
    float* __restrict__ out, const float* __restrict__ bias) {
  __shared__ unsigned short Alds[128 * 64];
  __shared__ unsigned short Blds[64 * 64];
  int widx = threadIdx.x >> 6, lane = threadIdx.x & 63;
  int blk = blockIdx.x;
  int nt = blk & 7, mt = blk >> 3;
  int blkM = mt * 128, blkN = nt * 64;
  int wr = widx >> 1, wc = widx & 1;
  int lr = lane & 15, lg = lane >> 4;
  int srow = lane >> 3, sc8 = lane & 7;

  f32x4 acc[4][2] = {};

  for (int kc = 0; kc < 512; kc += 64) {
#pragma unroll
    for (int i = 0; i < 4; ++i) {
      int rb = widx * 32 + i * 8;
      int row = rb + srow;
      int cs = (sc8 ^ (row & 7)) * 8;
      gload_lds16(A + (size_t)(blkM + row) * 512 + kc + cs, &Alds[rb * 64]);
    }
#pragma unroll
    for (int i = 0; i < 2; ++i) {
      int rb = widx * 16 + i * 8;
      int row = rb + srow;
      int cs = (sc8 ^ (row & 7)) * 8;
      gload_lds16(Wt + (size_t)(blkN + row) * 512 + kc + cs, &Blds[rb * 64]);
    }
    __syncthreads();

#pragma unroll
    for (int kh = 0; kh < 2; ++kh) {
      bf16x8 bfr[2];
#pragma unroll
      for (int ni = 0; ni < 2; ++ni) {
        int brow = wc * 32 + ni * 16 + lr;
        bfr[ni] = *(const bf16x8*)&Blds[brow * 64 + (((kh * 4 + lg) ^ (brow & 7)) * 8)];
      }
#pragma unroll
      for (int mi = 0; mi < 4; ++mi) {
        int arow = wr * 64 + mi * 16 + lr;
        bf16x8 afr = *(const bf16x8*)&Alds[arow * 64 + (((kh * 4 + lg) ^ (arow & 7)) * 8)];
#pragma unroll
        for (int ni = 0; ni < 2; ++ni)
          acc[mi][ni] = __builtin_amdgcn_mfma_f32_16x16x32_bf16(afr, bfr[ni], acc[mi][ni], 0, 0, 0);
      }
    }
    __syncthreads();
  }

#pragma unroll
  for (int mi = 0; mi < 4; ++mi)
#pragma unroll
    for (int ni = 0; ni < 2; ++ni) {
      int col = blkN + wc * 32 + ni * 16 + lr;
#pragma unroll
      for (int j = 0; j < 4; ++j) {
        int row = blkM + wr * 64 + mi * 16 + lg * 4 + j;
        out[(size_t)row * 512 + col] = acc[mi][ni][j] + bias[col];
      }
    }
}

// ---------------- flash attention, 32x32 MFMA, KVCHUNK=128 ----------------
// Block = 4 waves sharing one (b,h), each wave 32 q-rows; 512 blocks -> 2/CU.
// K/V staged in LDS: K [128 key][64 d] (3-bit XOR swz), V [64 d][128 key]
// (4-bit XOR swz, conflict-free). Double-buffered, one barrier pair per 128
// keys. Softmax math identical to R9-passing, run once per 64-key half.

#define KVCHUNK 128
#define NCHUNK (NSEQ / KVCHUNK)   // 16

#define STAGE(buf, kcc) do {                                              \
    _Pragma("unroll")                                                     \
    for (int i = 0; i < 4; ++i) {                                         \
      int rbk = widx * 32 + i * 8;                                        \
      int rowk = rbk + (lane >> 3);                                       \
      int csk = (lane & 7) ^ (rowk & 7);                                  \
      gload_lds16(Kg + (size_t)((kcc) + rowk) * 512 + csk * 8, &Klds[buf][rbk * 64]); \
      int rbv = widx * 16 + i * 4;                                        \
      int rowv = rbv + (lane >> 4);                                       \
      int csv = (lane & 15) ^ (rowv & 15);                                \
      gload_lds16(Vg + (size_t)rowv * NSEQ + (kcc) + csv * 8, &Vlds[buf][rbv * 128]); \
    }                                                                     \
  } while (0)

// process one 64-key half of the staged 128-key tile
#define PROCESS_LDS64(kb_, vb_, half) do {                                \
    f32x16 s[2];                                                          \
    __builtin_amdgcn_s_setprio(1);                                        \
    _Pragma("unroll")                                                     \
    for (int kt = 0; kt < 2; ++kt) {                                      \
      int krow = (half) * 64 + kt * 32 + ql;                              \
      f32x16 z = {};                                                      \
      _Pragma("unroll")                                                   \
      for (int ks = 0; ks < 4; ++ks) {                                    \
        bf16x8 kf = *(const bf16x8*)((kb_) + krow * 64 + (((ks * 2 + hi) ^ (krow & 7)) * 8)); \
        z = __builtin_amdgcn_mfma_f32_32x32x16_bf16(kf, qf[ks], z, 0, 0, 0); \
      }                                                                   \
      s[kt] = z;                                                          \
    }                                                                     \
    __builtin_amdgcn_s_setprio(0);                                        \
    float m8 = s[0][0];                                                   \
    _Pragma("unroll")                                                     \
    for (int i = 1; i < 16; ++i) m8 = fmaxf(m8, s[0][i]);                 \
    _Pragma("unroll")                                                     \
    for (int i = 0; i < 16; ++i) m8 = fmaxf(m8, s[1][i]);                 \
    m8 = fmaxf(m8, __shfl_xor(m8, 32));                                   \
    bool grow = (m8 > m0 + DEFER_THR);                                    \
    if (__any((int)grow)) {                                               \
      float mn = fmaxf(m0, m8);                                           \
      float al = fexp2(m0 - mn);                                          \
      m0 = mn; l0 *= al;                                                  \
      _Pragma("unroll")                                                   \
      for (int dt = 0; dt < 2; ++dt)                                      \
        _Pragma("unroll")                                                 \
        for (int j = 0; j < 16; ++j) o[dt][j] *= al;                      \
    }                                                                     \
    float p0[16], p1[16]; float rs = 0.f;                                 \
    _Pragma("unroll")                                                     \
    for (int i = 0; i < 16; ++i) { p0[i] = fexp2(s[0][i] - m0); rs += p0[i]; } \
    _Pragma("unroll")                                                     \
    for (int i = 0; i < 16; ++i) { p1[i] = fexp2(s[1][i] - m0); rs += p1[i]; } \
    rs += __shfl_xor(rs, 32);                                             \
    l0 += rs;                                                             \
    union { unsigned w[4]; bf16x8 v; } pf[4];                             \
    _Pragma("unroll")                                                     \
    for (int d2 = 0; d2 < 4; ++d2) {                                      \
      pf[0].w[d2] = cvt_pk_bf16(p0[2 * d2], p0[2 * d2 + 1]);              \
      pf[1].w[d2] = cvt_pk_bf16(p0[8 + 2 * d2], p0[8 + 2 * d2 + 1]);      \
      pf[2].w[d2] = cvt_pk_bf16(p1[2 * d2], p1[2 * d2 + 1]);              \
      pf[3].w[d2] = cvt_pk_bf16(p1[8 + 2 * d2], p1[8 + 2 * d2 + 1]);      \
    }                                                                     \
    __builtin_amdgcn_s_setprio(1);                                        \
    _Pragma("unroll")                                                     \
    for (int dt = 0; dt < 2; ++dt) {                                      \
      int vrow = dt * 32 + ql;                                            \
      f32x16 acc = o[dt];                                                 \
      _Pragma("unroll")                                                   \
      for (int g = 0; g < 4; ++g) {                                       \
        int sv = (half) * 8 + g * 2 + hi;                                 \
        bf16x8 vf = *(const bf16x8*)((vb_) + vrow * 128 + ((sv ^ (vrow & 15)) * 8)); \
        acc = __builtin_amdgcn_mfma_f32_32x32x16_bf16(vf, pf[g].v, acc, 0, 0, 0); \
      }                                                                   \
      o[dt] = acc;                                                        \
    }                                                                     \
    __builtin_amdgcn_s_setprio(0);                                        \
  } while (0)

__global__ __launch_bounds__(256, 2) void attn_kernel(
    const unsigned short* __restrict__ Q, const unsigned short* __restrict__ K,
    const unsigned short* __restrict__ VT, unsigned short* __restrict__ O) {
  __shared__ unsigned short Klds[2][128 * 64];
  __shared__ unsigned short Vlds[2][64 * 128];
  int widx = threadIdx.x >> 6, lane = threadIdx.x & 63;
  int blk = blockIdx.x;                // 0..511
  int xcd = blk & 7;
  int idx = blk >> 3;                  // 0..63 within XCD
  int bh = xcd * 4 + (idx >> 4);       // 0..31 (4 bh per XCD; all 4 waves share bh)
  int qg = idx & 15;                   // 128-row q-group within bh
  int b = bh >> 3, h = bh & 7;
  int ql = lane & 31, hi = lane >> 5;
  int qrow0 = qg * 128 + widx * 32;    // this wave's 32 q-rows

  // Q B-fragments: col q = ql, k-slice ks: d = ks*16 + hi*8 + j (pre-scaled)
  bf16x8 qf[4];
  const unsigned short* Qp = Q + (size_t)(b * NSEQ + qrow0 + ql) * 512 + h * 64 + hi * 8;
#pragma unroll
  for (int ks = 0; ks < 4; ++ks) qf[ks] = *(const bf16x8*)(Qp + ks * 16);

  const unsigned short* Kg = K + (size_t)b * NSEQ * 512 + h * 64;
  const unsigned short* Vg = VT + (size_t)bh * DH * NSEQ;

  float m0 = -3.0e38f, l0 = 0.f;
  f32x16 o[2] = {};

  STAGE(0, 0);
  __syncthreads();
  int cur = 0;
  for (int t = 0; t < NCHUNK; ++t) {
    if (t + 1 < NCHUNK) STAGE(cur ^ 1, (t + 1) * KVCHUNK);
    const unsigned short* kb_ = &Klds[cur][0];
    const unsigned short* vb_ = &Vlds[cur][0];
    PROCESS_LDS64(kb_, vb_, 0);
    PROCESS_LDS64(kb_, vb_, 1);
    __syncthreads();   // drains next-tile staging; guards LDS reuse
    cur ^= 1;
  }

  // epilogue: C layout row d=(r&3)+8(r>>2)+4hi, col q=ql
  {
    float inv = 1.f / l0;
    size_t rowb = (size_t)(b * NSEQ + qrow0 + ql) * 512 + h * 64 + hi * 4;
#pragma unroll
    for (int dt = 0; dt < 2; ++dt)
#pragma unroll
      for (int c = 0; c < 8; ++c) {
        unsigned w = cvt_pk_bf16(o[dt][2 * c] * inv, o[dt][2 * c + 1] * inv);
        int d0 = dt * 32 + 8 * (c >> 1) + (c & 1) * 2;
        *(unsigned*)(O + rowb + d0) = w;
      }
  }
}

extern "C" void kernel_launch(void* const* d_in, const int* in_sizes, int n_in,
                              void* d_out, int out_size, void* d_ws, size_t ws_size,
                              hipStream_t stream) {
  const float* x   = (const float*)d_in[0];
  const float* z   = (const float*)d_in[1];
  const float* lxg = (const float*)d_in[2];
  const float* lxb = (const float*)d_in[3];
  const float* lzg = (const float*)d_in[4];
  const float* lzb = (const float*)d_in[5];
  const float* Wq  = (const float*)d_in[6];
  const float* Wk  = (const float*)d_in[7];
  const float* Wv  = (const float*)d_in[8];
  const float* Wz  = (const float*)d_in[9];
  const float* Wo  = (const float*)d_in[10];
  const float* bo  = (const float*)d_in[11];

  char* ws = (char*)d_ws;
  unsigned short* xm  = (unsigned short*)(ws);
  unsigned short* qb  = (unsigned short*)(ws + 8388608);
  unsigned short* kb  = (unsigned short*)(ws + 16777216);
  unsigned short* vt  = (unsigned short*)(ws + 25165824);
  unsigned short* ao  = (unsigned short*)(ws + 33554432);
  unsigned short* wqt = (unsigned short*)(ws + 41943040);   // wq,wk,wv,wo contiguous
  unsigned short* wot = (unsigned short*)(ws + 43515904);
  float*          z12 = (float*)(ws + 44040192);

  zpath_kernel<<<NBATCH, 256, 0, stream>>>(z, lzg, lzb, Wz, z12);
  xmod_kernel<<<NROWS / 4, 256, 0, stream>>>(x, lxg, lxb, z12, xm);
  wtrans4_kernel<<<4096, 256, 0, stream>>>(Wq, Wk, Wv, Wo, wqt);
  gemm_qkv_kernel<<<768, 256, 0, stream>>>(xm, wqt, qb, kb, vt);
  attn_kernel<<<512, 256, 0, stream>>>(qb, kb, vt, ao);
  gemm_out_kernel<<<512, 256, 0, stream>>>(ao, wot, (float*)d_out, bo);
}